// Round 2
// baseline (6277.012 us; speedup 1.0000x reference)
//
#include <hip/hip_runtime.h>
#include <math.h>

#define D 512
#define NH 8
#define DH 64
#define HID 2048
#define NL 6
#define SEQ 512
#define BATCH 4
#define MROWS (BATCH * SEQ)   // 2048
#define NVT 16000
#define LNEPS 1e-5f

// ---------------------------------------------------------------------------
// Embedding + positional encoding: out[row, d] = emb[tok[row]][d] + pe[s][d]
// Precise libm trig: this runs once per token and feeds everything downstream.
// ---------------------------------------------------------------------------
__global__ __launch_bounds__(128) void embed_kernel(const int* __restrict__ toks,
                                                    const float* __restrict__ emb,
                                                    float* __restrict__ out) {
    const int row = blockIdx.x;            // b*SEQ + s
    const int s = row & (SEQ - 1);
    const int tok = toks[row];
    const int d = threadIdx.x * 4;
    float4 e = *(const float4*)&emb[tok * D + d];
    float r[4];
#pragma unroll
    for (int i = 0; i < 4; i += 2) {
        const int dd = d + i;
        const float dv = expf((float)dd * (-9.210340371976184f / (float)D));
        const float ang = (float)s * dv;
        r[i] = sinf(ang);
        r[i + 1] = cosf(ang);
    }
    float4 o;
    o.x = e.x + r[0]; o.y = e.y + r[1]; o.z = e.z + r[2]; o.w = e.w + r[3];
    *(float4*)&out[row * D + d] = o;
}

// ---------------------------------------------------------------------------
// Residual add + LayerNorm (in place on x): x = LN(x + r) * g + b
// one block (128 threads) per row of D=512
// ---------------------------------------------------------------------------
__global__ __launch_bounds__(128) void add_ln_kernel(float* __restrict__ x,
                                                     const float* __restrict__ r,
                                                     const float* __restrict__ g,
                                                     const float* __restrict__ b) {
    const int row = blockIdx.x;
    const int t = threadIdx.x;
    const int d = t * 4;
    float4 xv = *(const float4*)&x[row * D + d];
    float4 rv = *(const float4*)&r[row * D + d];
    float4 v;
    v.x = xv.x + rv.x; v.y = xv.y + rv.y; v.z = xv.z + rv.z; v.w = xv.w + rv.w;
    float s = v.x + v.y + v.z + v.w;
    float s2 = v.x * v.x + v.y * v.y + v.z * v.z + v.w * v.w;
#pragma unroll
    for (int off = 32; off > 0; off >>= 1) {
        s += __shfl_down(s, off);
        s2 += __shfl_down(s2, off);
    }
    __shared__ float sh[4];
    if ((t & 63) == 0) { sh[(t >> 6) * 2] = s; sh[(t >> 6) * 2 + 1] = s2; }
    __syncthreads();
    s = sh[0] + sh[2];
    s2 = sh[1] + sh[3];
    const float mean = s * (1.0f / D);
    const float var = s2 * (1.0f / D) - mean * mean;
    const float rstd = rsqrtf(var + LNEPS);
    float4 gv = *(const float4*)&g[d];
    float4 bv = *(const float4*)&b[d];
    float4 o;
    o.x = (v.x - mean) * rstd * gv.x + bv.x;
    o.y = (v.y - mean) * rstd * gv.y + bv.y;
    o.z = (v.z - mean) * rstd * gv.z + bv.z;
    o.w = (v.w - mean) * rstd * gv.w + bv.w;
    *(float4*)&x[row * D + d] = o;
}

// ---------------------------------------------------------------------------
// fp32 GEMM: C[M,N] = A[M,K] @ W[K,N] + bias[N], optional ReLU
// 64x64 tile, BK=16, 256 threads, 4x4 per thread, global->reg prefetch.
// z-batched: blockIdx.z selects weight/bias/output slice (QKV fusion);
//   A = A0 for z==0 else A1 (cross-attention has Q-input != KV-input).
// LDS rows padded to 68 floats: keeps float4 (16B) alignment and <=2-way banks
// ---------------------------------------------------------------------------
template <bool RELU>
__global__ __launch_bounds__(256) void gemm_kernel(const float* __restrict__ A0,
                                                   const float* __restrict__ A1,
                                                   const float* __restrict__ W,
                                                   const float* __restrict__ bias,
                                                   float* __restrict__ C,
                                                   int M, int N, int K,
                                                   size_t wz, size_t cz) {
    __shared__ float As[16][68];   // [k][m]
    __shared__ float Bs[16][68];   // [k][n]
    const float* A = (blockIdx.z == 0) ? A0 : A1;
    W += (size_t)blockIdx.z * wz;
    bias += (size_t)blockIdx.z * (size_t)N;
    C += (size_t)blockIdx.z * cz;

    const int tid = threadIdx.x;
    const int bm = blockIdx.y * 64;
    const int bn = blockIdx.x * 64;
    const int tx = tid & 15;       // n-group
    const int ty = tid >> 4;       // m-group
    const int am = tid >> 2;       // 0..63  (A tile row)
    const int ak = (tid & 3) * 4;  // 0,4,8,12
    const int wk = tid >> 4;       // 0..15  (W tile row)
    const int wn = (tid & 15) * 4; // 0..60
    const float* Aptr = A + (size_t)(bm + am) * K + ak;
    const float* Wptr = W + (size_t)wk * N + bn + wn;

    float acc[4][4] = {};
    // prefetch first tile
    float4 a4 = *(const float4*)(Aptr);
    float4 w4 = *(const float4*)(Wptr);
    for (int k0 = 0; k0 < K; k0 += 16) {
        As[ak + 0][am] = a4.x;
        As[ak + 1][am] = a4.y;
        As[ak + 2][am] = a4.z;
        As[ak + 3][am] = a4.w;
        *(float4*)&Bs[wk][wn] = w4;
        __syncthreads();
        if (k0 + 16 < K) {         // prefetch next tile while computing this one
            a4 = *(const float4*)(Aptr + k0 + 16);
            w4 = *(const float4*)(Wptr + (size_t)(k0 + 16) * N);
        }
#pragma unroll
        for (int kk = 0; kk < 16; ++kk) {
            float4 ar = *(const float4*)&As[kk][ty * 4];
            float4 br = *(const float4*)&Bs[kk][tx * 4];
            acc[0][0] += ar.x * br.x; acc[0][1] += ar.x * br.y; acc[0][2] += ar.x * br.z; acc[0][3] += ar.x * br.w;
            acc[1][0] += ar.y * br.x; acc[1][1] += ar.y * br.y; acc[1][2] += ar.y * br.z; acc[1][3] += ar.y * br.w;
            acc[2][0] += ar.z * br.x; acc[2][1] += ar.z * br.y; acc[2][2] += ar.z * br.z; acc[2][3] += ar.z * br.w;
            acc[3][0] += ar.w * br.x; acc[3][1] += ar.w * br.y; acc[3][2] += ar.w * br.z; acc[3][3] += ar.w * br.w;
        }
        __syncthreads();
    }
    float4 b4 = *(const float4*)&bias[bn + tx * 4];
#pragma unroll
    for (int i = 0; i < 4; ++i) {
        const int row = bm + ty * 4 + i;
        float4 o;
        o.x = acc[i][0] + b4.x; o.y = acc[i][1] + b4.y;
        o.z = acc[i][2] + b4.z; o.w = acc[i][3] + b4.w;
        if (RELU) {
            o.x = fmaxf(o.x, 0.0f); o.y = fmaxf(o.y, 0.0f);
            o.z = fmaxf(o.z, 0.0f); o.w = fmaxf(o.w, 0.0f);
        }
        *(float4*)&C[(size_t)row * N + bn + tx * 4] = o;
    }
}

// ---------------------------------------------------------------------------
// Fused attention for one (b, h, 16-query tile).
// Q,K,V layout: [B, SEQ, D] with head h occupying cols h*64 .. h*64+63.
// MODE 0: key masked where srctok==PAD (encoder self + cross)
// MODE 1: causal OR tgttok==PAD (decoder self)
// ---------------------------------------------------------------------------
template <int MODE>
__global__ __launch_bounds__(256) void attn_kernel(const float* __restrict__ Q,
                                                   const float* __restrict__ Km,
                                                   const float* __restrict__ Vm,
                                                   const int* __restrict__ toks,
                                                   float* __restrict__ O) {
    __shared__ float Qs[16][68];
    __shared__ float Ts[64][68];    // K tile, then V tile
    __shared__ float Sc[16][516];   // padded: stride 516 -> <=2-way on access
    __shared__ float rowinv[16];

    const int tid = threadIdx.x;
    const int bh = blockIdx.y;
    const int b = bh >> 3;
    const int h = bh & 7;
    const int q0 = blockIdx.x * 16;
    const size_t base = (size_t)b * SEQ * D + h * 64;
    const float scale = 0.125f;     // 1/sqrt(64)

    // load Q tile (16 x 64)
    {
        const int q = tid >> 4, dq = (tid & 15) * 4;
        *(float4*)&Qs[q][dq] = *(const float4*)&Q[base + (size_t)(q0 + q) * D + dq];
    }

    // ---- Phase 1: scores = Q @ K^T (masked, scaled) -> Sc ----
    const int q = tid & 15;       // query row this thread owns in phase 1
    const int ky = tid >> 4;      // 0..15; keys ky + 16*i, i in 0..3
    for (int kt = 0; kt < SEQ; kt += 64) {
        __syncthreads();
        {   // load K tile 64x64
            const int r = tid >> 4, c = (tid & 15) * 4;
#pragma unroll
            for (int i = 0; i < 4; ++i)
                *(float4*)&Ts[r + i * 16][c] =
                    *(const float4*)&Km[base + (size_t)(kt + r + i * 16) * D + c];
        }
        __syncthreads();
        float a0 = 0.f, a1 = 0.f, a2 = 0.f, a3 = 0.f;
#pragma unroll
        for (int d = 0; d < 64; d += 4) {
            float4 qv = *(const float4*)&Qs[q][d];
            float4 t0 = *(const float4*)&Ts[ky][d];
            float4 t1 = *(const float4*)&Ts[ky + 16][d];
            float4 t2 = *(const float4*)&Ts[ky + 32][d];
            float4 t3 = *(const float4*)&Ts[ky + 48][d];
            a0 += qv.x * t0.x + qv.y * t0.y + qv.z * t0.z + qv.w * t0.w;
            a1 += qv.x * t1.x + qv.y * t1.y + qv.z * t1.z + qv.w * t1.w;
            a2 += qv.x * t2.x + qv.y * t2.y + qv.z * t2.z + qv.w * t2.w;
            a3 += qv.x * t3.x + qv.y * t3.y + qv.z * t3.z + qv.w * t3.w;
        }
        const int qg = q0 + q;
        float sc[4] = {a0 * scale, a1 * scale, a2 * scale, a3 * scale};
#pragma unroll
        for (int i = 0; i < 4; ++i) {
            const int kg = kt + ky + 16 * i;
            bool masked;
            if (MODE == 0) masked = (toks[b * SEQ + kg] == 0);
            else           masked = (kg > qg) || (toks[b * SEQ + kg] == 0);
            Sc[q][kg] = masked ? -1e30f : sc[i];
        }
    }
    __syncthreads();

    // ---- Phase 2: softmax per row (16 lanes per row) ----
    {
        const int row = tid >> 4, j = tid & 15;
        float m = -1e30f;
        for (int c = j; c < SEQ; c += 16) m = fmaxf(m, Sc[row][c]);
#pragma unroll
        for (int off = 8; off > 0; off >>= 1) m = fmaxf(m, __shfl_xor(m, off, 16));
        float sum = 0.f;
        for (int c = j; c < SEQ; c += 16) {
            float e = __expf(Sc[row][c] - m);
            Sc[row][c] = e;
            sum += e;
        }
#pragma unroll
        for (int off = 8; off > 0; off >>= 1) sum += __shfl_xor(sum, off, 16);
        if (j == 0) rowinv[row] = 1.0f / sum;
    }

    // ---- Phase 3: O = P @ V ----
    const int oq = tid >> 4;          // 0..15
    const int od = (tid & 15) * 4;    // 0..60
    float4 o = {0.f, 0.f, 0.f, 0.f};
    for (int kt = 0; kt < SEQ; kt += 64) {
        __syncthreads();
        {   // load V tile 64x64
            const int r = tid >> 4, c = (tid & 15) * 4;
#pragma unroll
            for (int i = 0; i < 4; ++i)
                *(float4*)&Ts[r + i * 16][c] =
                    *(const float4*)&Vm[base + (size_t)(kt + r + i * 16) * D + c];
        }
        __syncthreads();
#pragma unroll 8
        for (int k = 0; k < 64; ++k) {
            const float p = Sc[oq][kt + k];
            float4 v4 = *(const float4*)&Ts[k][od];
            o.x += p * v4.x; o.y += p * v4.y; o.z += p * v4.z; o.w += p * v4.w;
        }
    }
    const float inv = rowinv[oq];
    o.x *= inv; o.y *= inv; o.z *= inv; o.w *= inv;
    *(float4*)&O[base + (size_t)(q0 + oq) * D + od] = o;
}

// ---------------------------------------------------------------------------
// Host-side orchestration
// ---------------------------------------------------------------------------
extern "C" void kernel_launch(void* const* d_in, const int* in_sizes, int n_in,
                              void* d_out, int out_size, void* d_ws, size_t ws_size,
                              hipStream_t stream) {
    const int* src = (const int*)d_in[0];
    const int* tgt = (const int*)d_in[1];
    const float* emb_src = (const float*)d_in[2];
    const float* emb_tgt = (const float*)d_in[3];
    const float* enc_attn_w = (const float*)d_in[4];
    const float* enc_attn_b = (const float*)d_in[5];
    const float* enc_ff_w1 = (const float*)d_in[6];
    const float* enc_ff_b1 = (const float*)d_in[7];
    const float* enc_ff_w2 = (const float*)d_in[8];
    const float* enc_ff_b2 = (const float*)d_in[9];
    const float* enc_ln_g = (const float*)d_in[10];
    const float* enc_ln_b = (const float*)d_in[11];
    const float* dec_attn_w = (const float*)d_in[12];
    const float* dec_attn_b = (const float*)d_in[13];
    const float* dec_ff_w1 = (const float*)d_in[14];
    const float* dec_ff_b1 = (const float*)d_in[15];
    const float* dec_ff_w2 = (const float*)d_in[16];
    const float* dec_ff_b2 = (const float*)d_in[17];
    const float* dec_ln_g = (const float*)d_in[18];
    const float* dec_ln_b = (const float*)d_in[19];
    const float* fc_w = (const float*)d_in[20];
    const float* fc_b = (const float*)d_in[21];
    float* out = (float*)d_out;

    float* ws = (float*)d_ws;
    const size_t NTOK = (size_t)MROWS * D;   // 2048*512 = 1M floats
    float* xe = ws;               // encoder activations
    float* xd = xe + NTOK;        // decoder activations
    float* qb = xd + NTOK;        // NOTE: qb,kb,vb contiguous (z-batched QKV)
    float* kb = qb + NTOK;
    float* vb = kb + NTOK;
    float* ab = vb + NTOK;        // attention output
    float* tb = ab + NTOK;        // projection / ffn-out temp
    float* hb = tb + NTOK;        // ffn hidden: 2048*2048 = 4M floats

    auto gemm = [&](const float* A, const float* W, const float* bias, float* C,
                    int M, int N, int K, bool relu) {
        dim3 grid(N / 64, M / 64, 1);
        if (relu)
            gemm_kernel<true><<<grid, 256, 0, stream>>>(A, A, W, bias, C, M, N, K, 0, 0);
        else
            gemm_kernel<false><<<grid, 256, 0, stream>>>(A, A, W, bias, C, M, N, K, 0, 0);
    };
    // fused Q,K,V projection: z=0 -> Q from Aq, z=1,2 -> K,V from Akv
    auto gemm_qkv = [&](const float* Aq, const float* Akv,
                        const float* w, const float* bi) {
        dim3 grid(D / 64, MROWS / 64, 3);
        gemm_kernel<false><<<grid, 256, 0, stream>>>(Aq, Akv, w, bi, qb,
                                                     MROWS, D, D,
                                                     (size_t)D * D, NTOK);
    };

    // embeddings + positional encoding
    embed_kernel<<<MROWS, 128, 0, stream>>>(src, emb_src, xe);
    embed_kernel<<<MROWS, 128, 0, stream>>>(tgt, emb_tgt, xd);

    const dim3 attn_grid(SEQ / 16, BATCH * NH);

    // ---------------- encoder ----------------
    for (int l = 0; l < NL; ++l) {
        const float* w = enc_attn_w + (size_t)l * 4 * D * D;
        const float* bi = enc_attn_b + (size_t)l * 4 * D;
        gemm_qkv(xe, xe, w, bi);
        attn_kernel<0><<<attn_grid, 256, 0, stream>>>(qb, kb, vb, src, ab);
        gemm(ab, w + 3 * D * D, bi + 3 * D, tb, MROWS, D, D, false);
        add_ln_kernel<<<MROWS, 128, 0, stream>>>(xe, tb,
            enc_ln_g + (size_t)(l * 2 + 0) * D, enc_ln_b + (size_t)(l * 2 + 0) * D);
        gemm(xe, enc_ff_w1 + (size_t)l * D * HID, enc_ff_b1 + (size_t)l * HID, hb,
             MROWS, HID, D, true);
        gemm(hb, enc_ff_w2 + (size_t)l * HID * D, enc_ff_b2 + (size_t)l * D, tb,
             MROWS, D, HID, false);
        add_ln_kernel<<<MROWS, 128, 0, stream>>>(xe, tb,
            enc_ln_g + (size_t)(l * 2 + 1) * D, enc_ln_b + (size_t)(l * 2 + 1) * D);
    }

    // ---------------- decoder ----------------
    for (int l = 0; l < NL; ++l) {
        // self-attention (causal + tgt pad mask)
        {
            const float* w = dec_attn_w + (size_t)(l * 2 + 0) * 4 * D * D;
            const float* bi = dec_attn_b + (size_t)(l * 2 + 0) * 4 * D;
            gemm_qkv(xd, xd, w, bi);
            attn_kernel<1><<<attn_grid, 256, 0, stream>>>(qb, kb, vb, tgt, ab);
            gemm(ab, w + 3 * D * D, bi + 3 * D, tb, MROWS, D, D, false);
            add_ln_kernel<<<MROWS, 128, 0, stream>>>(xd, tb,
                dec_ln_g + (size_t)(l * 3 + 0) * D, dec_ln_b + (size_t)(l * 3 + 0) * D);
        }
        // cross-attention (src pad mask): Q from xd, K/V from xe
        {
            const float* w = dec_attn_w + (size_t)(l * 2 + 1) * 4 * D * D;
            const float* bi = dec_attn_b + (size_t)(l * 2 + 1) * 4 * D;
            gemm_qkv(xd, xe, w, bi);
            attn_kernel<0><<<attn_grid, 256, 0, stream>>>(qb, kb, vb, src, ab);
            gemm(ab, w + 3 * D * D, bi + 3 * D, tb, MROWS, D, D, false);
            add_ln_kernel<<<MROWS, 128, 0, stream>>>(xd, tb,
                dec_ln_g + (size_t)(l * 3 + 1) * D, dec_ln_b + (size_t)(l * 3 + 1) * D);
        }
        // FFN
        gemm(xd, dec_ff_w1 + (size_t)l * D * HID, dec_ff_b1 + (size_t)l * HID, hb,
             MROWS, HID, D, true);
        gemm(hb, dec_ff_w2 + (size_t)l * HID * D, dec_ff_b2 + (size_t)l * D, tb,
             MROWS, D, HID, false);
        add_ln_kernel<<<MROWS, 128, 0, stream>>>(xd, tb,
            dec_ln_g + (size_t)(l * 3 + 2) * D, dec_ln_b + (size_t)(l * 3 + 2) * D);
    }

    // final projection -> logits [B*T, VT]
    gemm(xd, fc_w, fc_b, out, MROWS, NVT, D, false);
}

// Round 4
// 4580.350 us; speedup vs baseline: 1.3704x; 1.3704x over previous
//
#include <hip/hip_runtime.h>
#include <math.h>

#define D 512
#define NH 8
#define DH 64
#define HID 2048
#define NL 6
#define SEQ 512
#define BATCH 4
#define MROWS (BATCH * SEQ)   // 2048
#define NVT 16000
#define LNEPS 1e-5f

typedef __attribute__((ext_vector_type(8))) short short8;
typedef __attribute__((ext_vector_type(4))) float f32x4;

// ---------------------------------------------------------------------------
// bf16 split: a = hi + lo, hi = truncate-to-bf16(a) (exact), lo = rtne(a-hi).
// ---------------------------------------------------------------------------
__device__ __forceinline__ ushort bf16_rtne(float f) {
    uint u = __builtin_bit_cast(uint, f);
    return (ushort)((u + 0x7fffu + ((u >> 16) & 1u)) >> 16);
}
// pack hi/lo parts of two consecutive elements into u32 (ushort[0]=first)
__device__ __forceinline__ void split2(float a, float b, uint& hi, uint& lo) {
    uint ua = __builtin_bit_cast(uint, a), ub = __builtin_bit_cast(uint, b);
    hi = (ua >> 16) | (ub & 0xffff0000u);
    float ra = a - __builtin_bit_cast(float, ua & 0xffff0000u);
    float rb = b - __builtin_bit_cast(float, ub & 0xffff0000u);
    lo = (uint)bf16_rtne(ra) | ((uint)bf16_rtne(rb) << 16);
}

// ---------------------------------------------------------------------------
// Weight transpose + bf16 split: src[K][N] fp32 -> dstH/dstL[N][K] bf16.
// 64x64 tiles via LDS [64][65] (2-way max bank aliasing on both sides).
// grid (N/64, K/64, nz); z adds zstride elements to src and dst.
// ---------------------------------------------------------------------------
__global__ __launch_bounds__(256) void wsplit_kernel(const float* __restrict__ src,
                                                     ushort* __restrict__ dstH,
                                                     ushort* __restrict__ dstL,
                                                     int K, int N, size_t zstride) {
    __shared__ float T[64][65];
    src += (size_t)blockIdx.z * zstride;
    dstH += (size_t)blockIdx.z * zstride;
    dstL += (size_t)blockIdx.z * zstride;
    const int t = threadIdx.x;
    const int n0 = blockIdx.x * 64;
    const int k0 = blockIdx.y * 64;
    {   // coalesced fp32 tile load (rows = k, cols = n)
        const int kr = t >> 4, nc = (t & 15) * 4;
#pragma unroll
        for (int i = 0; i < 4; ++i) {
            float4 v = *(const float4*)&src[(size_t)(k0 + kr + 16 * i) * N + n0 + nc];
            T[kr + 16 * i][nc + 0] = v.x;
            T[kr + 16 * i][nc + 1] = v.y;
            T[kr + 16 * i][nc + 2] = v.z;
            T[kr + 16 * i][nc + 3] = v.w;
        }
    }
    __syncthreads();
    // each thread: output row n = t>>2, k-chunk (t&3)*16
    const int n = t >> 2;
    const int kc = (t & 3) * 16;
    uint h[8], l[8];
#pragma unroll
    for (int i = 0; i < 8; ++i)
        split2(T[kc + 2 * i][n], T[kc + 2 * i + 1][n], h[i], l[i]);
    ushort* dh = &dstH[(size_t)(n0 + n) * K + k0 + kc];
    ushort* dl = &dstL[(size_t)(n0 + n) * K + k0 + kc];
    *(uint4*)(dh + 0) = uint4{h[0], h[1], h[2], h[3]};
    *(uint4*)(dh + 8) = uint4{h[4], h[5], h[6], h[7]};
    *(uint4*)(dl + 0) = uint4{l[0], l[1], l[2], l[3]};
    *(uint4*)(dl + 8) = uint4{l[4], l[5], l[6], l[7]};
}

// ---------------------------------------------------------------------------
// Split-bf16 (bf16x3) MFMA GEMM: C[M,N] = A[M,K] @ W[K,N] + bias, opt ReLU.
// A fp32 (converted hi/lo during staging); W pre-transposed bf16 [N][K] hi/lo.
// BOTH operands staged in LDS as rows of 32 CONSECUTIVE k (identity layout on
// both sides -> any hardware k-permutation cancels; fragment = 1 ds_read_b128
// of 8 consecutive bf16 at [row][8*(lane>>4)], rows padded to 40 ushort/80B).
// BK=32, 256 threads = 4 waves (2x2), wave tile (BM/2)x(BN/2), 16x16x32 MFMA.
// grid (M/BM, N/BN, z): m-major (consecutive blocks share the W panel).
// z-batch: W/bias/C slices (QKV fusion); A = z ? A1 : A0.
// ---------------------------------------------------------------------------
template <int BM, int BN, bool RELU>
__global__ __launch_bounds__(256) void gemm_mfma(const float* __restrict__ A0,
                                                 const float* __restrict__ A1,
                                                 const ushort* __restrict__ WTh,
                                                 const ushort* __restrict__ WTl,
                                                 const float* __restrict__ bias,
                                                 float* __restrict__ C,
                                                 int M, int N, int K,
                                                 size_t wz, size_t cz) {
    constexpr int FM = BM / 32;          // m-frags per wave
    constexpr int FN = BN / 32;          // n-frags per wave
    constexpr int EA = BM / 32;          // A: float4 staging loads / thread
    constexpr int EB = BN / 64;          // B: ushort8 staging loads / thread / plane
    constexpr int AROW = 40;             // ushort row stride (80 B, 16B-aligned)

    __shared__ ushort Ah[BM * AROW];
    __shared__ ushort Al[BM * AROW];
    __shared__ ushort Bh[BN * AROW];
    __shared__ ushort Bl[BN * AROW];

    const float* A = (blockIdx.z == 0) ? A0 : A1;
    WTh += (size_t)blockIdx.z * wz;
    WTl += (size_t)blockIdx.z * wz;
    bias += (size_t)blockIdx.z * (size_t)N;
    C += (size_t)blockIdx.z * cz;

    const int tid = threadIdx.x;
    const int lane = tid & 63;
    const int wv = tid >> 6;
    const int wm = wv >> 1, wn = wv & 1;
    const int bm = blockIdx.x * BM;
    const int bn = blockIdx.y * BN;

    // A staging map: thread covers A[bm + 32i + (tid>>3)][k0 + (tid&7)*4 ..+3]
    const int a_m = tid >> 3;
    const int a_kk = (tid & 7) * 4;
    // B staging map: thread covers WT[bn + 64i + (tid>>2)][k0 + (tid&3)*8 ..+7]
    const int b_n = tid >> 2;
    const int b_kq = (tid & 3) * 8;

    const float* aP[EA];
#pragma unroll
    for (int i = 0; i < EA; ++i)
        aP[i] = A + (size_t)(bm + 32 * i + a_m) * K + a_kk;
    const ushort* bPh[EB];
    const ushort* bPl[EB];
#pragma unroll
    for (int i = 0; i < EB; ++i) {
        const size_t off = (size_t)(bn + 64 * i + b_n) * K + b_kq;
        bPh[i] = WTh + off;
        bPl[i] = WTl + off;
    }

    f32x4 apre[EA];
    uint4 bhpre[EB], blpre[EB];
#pragma unroll
    for (int i = 0; i < EA; ++i) apre[i] = *(const f32x4*)(aP[i]);
#pragma unroll
    for (int i = 0; i < EB; ++i) {
        bhpre[i] = *(const uint4*)(bPh[i]);
        blpre[i] = *(const uint4*)(bPl[i]);
    }

    f32x4 acc[FM][FN] = {};

    const int NT = K >> 5;
    for (int kt = 0; kt < NT; ++kt) {
        // ---- stage prefetched regs into LDS ----
#pragma unroll
        for (int i = 0; i < EA; ++i) {
            uint h0, l0, h1, l1;
            split2(apre[i][0], apre[i][1], h0, l0);
            split2(apre[i][2], apre[i][3], h1, l1);
            const int idx = (32 * i + a_m) * AROW + a_kk;
            *(uint2*)&Ah[idx] = uint2{h0, h1};
            *(uint2*)&Al[idx] = uint2{l0, l1};
        }
#pragma unroll
        for (int i = 0; i < EB; ++i) {
            const int idx = (64 * i + b_n) * AROW + b_kq;
            *(uint4*)&Bh[idx] = bhpre[i];
            *(uint4*)&Bl[idx] = blpre[i];
        }
        __syncthreads();

        // ---- prefetch next k-tile ----
        if (kt + 1 < NT) {
            const int ko = (kt + 1) * 32;
#pragma unroll
            for (int i = 0; i < EA; ++i) apre[i] = *(const f32x4*)(aP[i] + ko);
#pragma unroll
            for (int i = 0; i < EB; ++i) {
                bhpre[i] = *(const uint4*)(bPh[i] + ko);
                blpre[i] = *(const uint4*)(bPl[i] + ko);
            }
        }

        // ---- fragment reads (one b128 each) ----
        const int g8 = (lane >> 4) * 8;
        short8 afh[FM], afl[FM], bfh[FN], bfl[FN];
#pragma unroll
        for (int mi = 0; mi < FM; ++mi) {
            const int o = (wm * (BM / 2) + mi * 16 + (lane & 15)) * AROW + g8;
            afh[mi] = *(const short8*)&Ah[o];
            afl[mi] = *(const short8*)&Al[o];
        }
#pragma unroll
        for (int ni = 0; ni < FN; ++ni) {
            const int o = (wn * (BN / 2) + ni * 16 + (lane & 15)) * AROW + g8;
            bfh[ni] = *(const short8*)&Bh[o];
            bfl[ni] = *(const short8*)&Bl[o];
        }

        // ---- MFMA: hh + hl + lh per fragment pair ----
#pragma unroll
        for (int ni = 0; ni < FN; ++ni)
#pragma unroll
            for (int mi = 0; mi < FM; ++mi) {
                acc[mi][ni] = __builtin_amdgcn_mfma_f32_16x16x32_bf16(afh[mi], bfh[ni], acc[mi][ni], 0, 0, 0);
                acc[mi][ni] = __builtin_amdgcn_mfma_f32_16x16x32_bf16(afh[mi], bfl[ni], acc[mi][ni], 0, 0, 0);
                acc[mi][ni] = __builtin_amdgcn_mfma_f32_16x16x32_bf16(afl[mi], bfh[ni], acc[mi][ni], 0, 0, 0);
            }
        __syncthreads();
    }

    // ---- epilogue: C/D layout col=lane&15, row=(lane>>4)*4+reg (m89) ----
#pragma unroll
    for (int ni = 0; ni < FN; ++ni) {
        const int col = bn + wn * (BN / 2) + ni * 16 + (lane & 15);
        const float bv = bias[col];
#pragma unroll
        for (int mi = 0; mi < FM; ++mi) {
            const int r0 = bm + wm * (BM / 2) + mi * 16 + (lane >> 4) * 4;
#pragma unroll
            for (int r = 0; r < 4; ++r) {
                float v = acc[mi][ni][r] + bv;
                if (RELU) v = fmaxf(v, 0.0f);
                C[(size_t)(r0 + r) * N + col] = v;
            }
        }
    }
}

// ---------------------------------------------------------------------------
// Embedding + positional encoding (validated round 2)
// ---------------------------------------------------------------------------
__global__ __launch_bounds__(128) void embed_kernel(const int* __restrict__ toks,
                                                    const float* __restrict__ emb,
                                                    float* __restrict__ out) {
    const int row = blockIdx.x;
    const int s = row & (SEQ - 1);
    const int tok = toks[row];
    const int d = threadIdx.x * 4;
    float4 e = *(const float4*)&emb[tok * D + d];
    float r[4];
#pragma unroll
    for (int i = 0; i < 4; i += 2) {
        const int dd = d + i;
        const float dv = expf((float)dd * (-9.210340371976184f / (float)D));
        const float ang = (float)s * dv;
        r[i] = sinf(ang);
        r[i + 1] = cosf(ang);
    }
    float4 o;
    o.x = e.x + r[0]; o.y = e.y + r[1]; o.z = e.z + r[2]; o.w = e.w + r[3];
    *(float4*)&out[row * D + d] = o;
}

// ---------------------------------------------------------------------------
// Residual add + LayerNorm (validated round 2)
// ---------------------------------------------------------------------------
__global__ __launch_bounds__(128) void add_ln_kernel(float* __restrict__ x,
                                                     const float* __restrict__ r,
                                                     const float* __restrict__ g,
                                                     const float* __restrict__ b) {
    const int row = blockIdx.x;
    const int t = threadIdx.x;
    const int d = t * 4;
    float4 xv = *(const float4*)&x[row * D + d];
    float4 rv = *(const float4*)&r[row * D + d];
    float4 v;
    v.x = xv.x + rv.x; v.y = xv.y + rv.y; v.z = xv.z + rv.z; v.w = xv.w + rv.w;
    float s = v.x + v.y + v.z + v.w;
    float s2 = v.x * v.x + v.y * v.y + v.z * v.z + v.w * v.w;
#pragma unroll
    for (int off = 32; off > 0; off >>= 1) {
        s += __shfl_down(s, off);
        s2 += __shfl_down(s2, off);
    }
    __shared__ float sh[4];
    if ((t & 63) == 0) { sh[(t >> 6) * 2] = s; sh[(t >> 6) * 2 + 1] = s2; }
    __syncthreads();
    s = sh[0] + sh[2];
    s2 = sh[1] + sh[3];
    const float mean = s * (1.0f / D);
    const float var = s2 * (1.0f / D) - mean * mean;
    const float rstd = rsqrtf(var + LNEPS);
    float4 gv = *(const float4*)&g[d];
    float4 bv = *(const float4*)&b[d];
    float4 o;
    o.x = (v.x - mean) * rstd * gv.x + bv.x;
    o.y = (v.y - mean) * rstd * gv.y + bv.y;
    o.z = (v.z - mean) * rstd * gv.z + bv.z;
    o.w = (v.w - mean) * rstd * gv.w + bv.w;
    *(float4*)&x[row * D + d] = o;
}

// ---------------------------------------------------------------------------
// Fused attention (fp32, validated round 2)
// MODE 0: key masked where srctok==PAD; MODE 1: causal | tgttok==PAD
// ---------------------------------------------------------------------------
template <int MODE>
__global__ __launch_bounds__(256) void attn_kernel(const float* __restrict__ Q,
                                                   const float* __restrict__ Km,
                                                   const float* __restrict__ Vm,
                                                   const int* __restrict__ toks,
                                                   float* __restrict__ O) {
    __shared__ float Qs[16][68];
    __shared__ float Ts[64][68];
    __shared__ float Sc[16][516];
    __shared__ float rowinv[16];

    const int tid = threadIdx.x;
    const int bh = blockIdx.y;
    const int b = bh >> 3;
    const int h = bh & 7;
    const int q0 = blockIdx.x * 16;
    const size_t base = (size_t)b * SEQ * D + h * 64;
    const float scale = 0.125f;

    {
        const int q = tid >> 4, dq = (tid & 15) * 4;
        *(float4*)&Qs[q][dq] = *(const float4*)&Q[base + (size_t)(q0 + q) * D + dq];
    }

    const int q = tid & 15;
    const int ky = tid >> 4;
    for (int kt = 0; kt < SEQ; kt += 64) {
        __syncthreads();
        {
            const int r = tid >> 4, c = (tid & 15) * 4;
#pragma unroll
            for (int i = 0; i < 4; ++i)
                *(float4*)&Ts[r + i * 16][c] =
                    *(const float4*)&Km[base + (size_t)(kt + r + i * 16) * D + c];
        }
        __syncthreads();
        float a0 = 0.f, a1 = 0.f, a2 = 0.f, a3 = 0.f;
#pragma unroll
        for (int d = 0; d < 64; d += 4) {
            float4 qv = *(const float4*)&Qs[q][d];
            float4 t0 = *(const float4*)&Ts[ky][d];
            float4 t1 = *(const float4*)&Ts[ky + 16][d];
            float4 t2 = *(const float4*)&Ts[ky + 32][d];
            float4 t3 = *(const float4*)&Ts[ky + 48][d];
            a0 += qv.x * t0.x + qv.y * t0.y + qv.z * t0.z + qv.w * t0.w;
            a1 += qv.x * t1.x + qv.y * t1.y + qv.z * t1.z + qv.w * t1.w;
            a2 += qv.x * t2.x + qv.y * t2.y + qv.z * t2.z + qv.w * t2.w;
            a3 += qv.x * t3.x + qv.y * t3.y + qv.z * t3.z + qv.w * t3.w;
        }
        const int qg = q0 + q;
        float sc[4] = {a0 * scale, a1 * scale, a2 * scale, a3 * scale};
#pragma unroll
        for (int i = 0; i < 4; ++i) {
            const int kg = kt + ky + 16 * i;
            bool masked;
            if (MODE == 0) masked = (toks[b * SEQ + kg] == 0);
            else           masked = (kg > qg) || (toks[b * SEQ + kg] == 0);
            Sc[q][kg] = masked ? -1e30f : sc[i];
        }
    }
    __syncthreads();

    {
        const int row = tid >> 4, j = tid & 15;
        float m = -1e30f;
        for (int c = j; c < SEQ; c += 16) m = fmaxf(m, Sc[row][c]);
#pragma unroll
        for (int off = 8; off > 0; off >>= 1) m = fmaxf(m, __shfl_xor(m, off, 16));
        float sum = 0.f;
        for (int c = j; c < SEQ; c += 16) {
            float e = __expf(Sc[row][c] - m);
            Sc[row][c] = e;
            sum += e;
        }
#pragma unroll
        for (int off = 8; off > 0; off >>= 1) sum += __shfl_xor(sum, off, 16);
        if (j == 0) rowinv[row] = 1.0f / sum;
    }

    const int oq = tid >> 4;
    const int od = (tid & 15) * 4;
    float4 o = {0.f, 0.f, 0.f, 0.f};
    for (int kt = 0; kt < SEQ; kt += 64) {
        __syncthreads();
        {
            const int r = tid >> 4, c = (tid & 15) * 4;
#pragma unroll
            for (int i = 0; i < 4; ++i)
                *(float4*)&Ts[r + i * 16][c] =
                    *(const float4*)&Vm[base + (size_t)(kt + r + i * 16) * D + c];
        }
        __syncthreads();
#pragma unroll 8
        for (int k = 0; k < 64; ++k) {
            const float p = Sc[oq][kt + k];
            float4 v4 = *(const float4*)&Ts[k][od];
            o.x += p * v4.x; o.y += p * v4.y; o.z += p * v4.z; o.w += p * v4.w;
        }
    }
    const float inv = rowinv[oq];
    o.x *= inv; o.y *= inv; o.z *= inv; o.w *= inv;
    *(float4*)&O[base + (size_t)(q0 + oq) * D + od] = o;
}

// ---------------------------------------------------------------------------
// Host-side orchestration
// ---------------------------------------------------------------------------
extern "C" void kernel_launch(void* const* d_in, const int* in_sizes, int n_in,
                              void* d_out, int out_size, void* d_ws, size_t ws_size,
                              hipStream_t stream) {
    const int* src = (const int*)d_in[0];
    const int* tgt = (const int*)d_in[1];
    const float* emb_src = (const float*)d_in[2];
    const float* emb_tgt = (const float*)d_in[3];
    const float* enc_attn_w = (const float*)d_in[4];
    const float* enc_attn_b = (const float*)d_in[5];
    const float* enc_ff_w1 = (const float*)d_in[6];
    const float* enc_ff_b1 = (const float*)d_in[7];
    const float* enc_ff_w2 = (const float*)d_in[8];
    const float* enc_ff_b2 = (const float*)d_in[9];
    const float* enc_ln_g = (const float*)d_in[10];
    const float* enc_ln_b = (const float*)d_in[11];
    const float* dec_attn_w = (const float*)d_in[12];
    const float* dec_attn_b = (const float*)d_in[13];
    const float* dec_ff_w1 = (const float*)d_in[14];
    const float* dec_ff_b1 = (const float*)d_in[15];
    const float* dec_ff_w2 = (const float*)d_in[16];
    const float* dec_ff_b2 = (const float*)d_in[17];
    const float* dec_ln_g = (const float*)d_in[18];
    const float* dec_ln_b = (const float*)d_in[19];
    const float* fc_w = (const float*)d_in[20];
    const float* fc_b = (const float*)d_in[21];
    float* out = (float*)d_out;

    float* ws = (float*)d_ws;
    const size_t NTOK = (size_t)MROWS * D;   // 1M floats
    float* xe = ws;
    float* xd = xe + NTOK;
    float* qb = xd + NTOK;        // qb,kb,vb contiguous (z-batched QKV)
    float* kb = qb + NTOK;
    float* vb = kb + NTOK;
    float* ab = vb + NTOK;
    float* tb = ab + NTOK;
    float* hb = tb + NTOK;        // 4M floats
    // transposed-weight arena (ushort), after the 11M-float activation region
    ushort* u0 = (ushort*)(hb + (size_t)MROWS * HID);
    const size_t DD = (size_t)D * D;
    ushort* wAh = u0;                       // up to 8 * D*D (dec attn)
    ushort* wAl = wAh + 8 * DD;
    ushort* wF1h = wAl + 8 * DD;            // D*HID
    ushort* wF1l = wF1h + DD * 4;           // D*HID = 4*DD
    ushort* wF2h = wF1l + DD * 4;
    ushort* wF2l = wF2h + DD * 4;
    ushort* wFCh = wF2l + DD * 4;           // D*NVT
    ushort* wFCl = wFCh + (size_t)D * NVT;

    auto transpose = [&](const float* w, ushort* dh, ushort* dl, int K, int N, int nz) {
        dim3 grid(N / 64, K / 64, nz);
        wsplit_kernel<<<grid, 256, 0, stream>>>(w, dh, dl, K, N, (size_t)K * N);
    };
    auto gemm64 = [&](const float* A, const ushort* WTh, const ushort* WTl,
                      const float* bias, float* C, int M, int N, int K) {
        dim3 grid(M / 64, N / 64, 1);
        gemm_mfma<64, 64, false><<<grid, 256, 0, stream>>>(A, A, WTh, WTl, bias, C, M, N, K, 0, 0);
    };
    auto gemm128 = [&](const float* A, const ushort* WTh, const ushort* WTl,
                       const float* bias, float* C, int M, int N, int K, bool relu) {
        dim3 grid(M / 128, N / 128, 1);
        if (relu)
            gemm_mfma<128, 128, true><<<grid, 256, 0, stream>>>(A, A, WTh, WTl, bias, C, M, N, K, 0, 0);
        else
            gemm_mfma<128, 128, false><<<grid, 256, 0, stream>>>(A, A, WTh, WTl, bias, C, M, N, K, 0, 0);
    };
    // fused Q,K,V projection: z=0 -> Q from Aq; z=1,2 -> K,V from Akv
    auto gemm_qkv = [&](const float* Aq, const float* Akv,
                        const ushort* WTh, const ushort* WTl, const float* bi) {
        dim3 grid(MROWS / 128, D / 128, 3);
        gemm_mfma<128, 128, false><<<grid, 256, 0, stream>>>(Aq, Akv, WTh, WTl, bi, qb,
                                                             MROWS, D, D, DD, NTOK);
    };

    embed_kernel<<<MROWS, 128, 0, stream>>>(src, emb_src, xe);
    embed_kernel<<<MROWS, 128, 0, stream>>>(tgt, emb_tgt, xd);

    const dim3 attn_grid(SEQ / 16, BATCH * NH);

    // ---------------- encoder ----------------
    for (int l = 0; l < NL; ++l) {
        const float* bi = enc_attn_b + (size_t)l * 4 * D;
        transpose(enc_attn_w + (size_t)l * 4 * DD, wAh, wAl, D, D, 4);
        transpose(enc_ff_w1 + (size_t)l * D * HID, wF1h, wF1l, D, HID, 1);
        transpose(enc_ff_w2 + (size_t)l * HID * D, wF2h, wF2l, HID, D, 1);

        gemm_qkv(xe, xe, wAh, wAl, bi);
        attn_kernel<0><<<attn_grid, 256, 0, stream>>>(qb, kb, vb, src, ab);
        gemm64(ab, wAh + 3 * DD, wAl + 3 * DD, bi + 3 * D, tb, MROWS, D, D);
        add_ln_kernel<<<MROWS, 128, 0, stream>>>(xe, tb,
            enc_ln_g + (size_t)(l * 2 + 0) * D, enc_ln_b + (size_t)(l * 2 + 0) * D);
        gemm128(xe, wF1h, wF1l, enc_ff_b1 + (size_t)l * HID, hb, MROWS, HID, D, true);
        gemm64(hb, wF2h, wF2l, enc_ff_b2 + (size_t)l * D, tb, MROWS, D, HID);
        add_ln_kernel<<<MROWS, 128, 0, stream>>>(xe, tb,
            enc_ln_g + (size_t)(l * 2 + 1) * D, enc_ln_b + (size_t)(l * 2 + 1) * D);
    }

    // ---------------- decoder ----------------
    for (int l = 0; l < NL; ++l) {
        transpose(dec_attn_w + (size_t)l * 8 * DD, wAh, wAl, D, D, 8);
        transpose(dec_ff_w1 + (size_t)l * D * HID, wF1h, wF1l, D, HID, 1);
        transpose(dec_ff_w2 + (size_t)l * HID * D, wF2h, wF2l, HID, D, 1);
        {   // self-attention (causal + tgt pad mask): slabs 0-3
            const float* bi = dec_attn_b + (size_t)(l * 2 + 0) * 4 * D;
            gemm_qkv(xd, xd, wAh, wAl, bi);
            attn_kernel<1><<<attn_grid, 256, 0, stream>>>(qb, kb, vb, tgt, ab);
            gemm64(ab, wAh + 3 * DD, wAl + 3 * DD, bi + 3 * D, tb, MROWS, D, D);
            add_ln_kernel<<<MROWS, 128, 0, stream>>>(xd, tb,
                dec_ln_g + (size_t)(l * 3 + 0) * D, dec_ln_b + (size_t)(l * 3 + 0) * D);
        }
        {   // cross-attention: Q from xd, K/V from xe: slabs 4-7
            const float* bi = dec_attn_b + (size_t)(l * 2 + 1) * 4 * D;
            gemm_qkv(xd, xe, wAh + 4 * DD, wAl + 4 * DD, bi);
            attn_kernel<0><<<attn_grid, 256, 0, stream>>>(qb, kb, vb, src, ab);
            gemm64(ab, wAh + 7 * DD, wAl + 7 * DD, bi + 3 * D, tb, MROWS, D, D);
            add_ln_kernel<<<MROWS, 128, 0, stream>>>(xd, tb,
                dec_ln_g + (size_t)(l * 3 + 1) * D, dec_ln_b + (size_t)(l * 3 + 1) * D);
        }
        gemm128(xd, wF1h, wF1l, dec_ff_b1 + (size_t)l * HID, hb, MROWS, HID, D, true);
        gemm64(hb, wF2h, wF2l, dec_ff_b2 + (size_t)l * D, tb, MROWS, D, HID);
        add_ln_kernel<<<MROWS, 128, 0, stream>>>(xd, tb,
            dec_ln_g + (size_t)(l * 3 + 2) * D, dec_ln_b + (size_t)(l * 3 + 2) * D);
    }

    // final projection -> logits [B*T, VT]
    transpose(fc_w, wFCh, wFCl, D, NVT, 1);
    {
        dim3 grid(MROWS / 128, NVT / 128, 1);
        gemm_mfma<128, 128, false><<<grid, 256, 0, stream>>>(xd, xd, wFCh, wFCl, fc_b, out,
                                                             MROWS, NVT, D, 0, 0);
    }
}

// Round 5
// 2871.070 us; speedup vs baseline: 2.1863x; 1.5953x over previous
//
#include <hip/hip_runtime.h>
#include <math.h>

#define D 512
#define NH 8
#define DH 64
#define HID 2048
#define NL 6
#define SEQ 512
#define BATCH 4
#define MROWS (BATCH * SEQ)   // 2048
#define NVT 16000
#define LNEPS 1e-5f

typedef __attribute__((ext_vector_type(8))) short short8;
typedef __attribute__((ext_vector_type(4))) float f32x4;

// ---------------------------------------------------------------------------
// bf16 split: a = hi + lo, hi = truncate-to-bf16(a) (exact), lo = rtne(a-hi).
// ---------------------------------------------------------------------------
__device__ __forceinline__ ushort bf16_rtne(float f) {
    uint u = __builtin_bit_cast(uint, f);
    return (ushort)((u + 0x7fffu + ((u >> 16) & 1u)) >> 16);
}
// pack hi/lo parts of two consecutive elements into u32 (ushort[0]=first)
__device__ __forceinline__ void split2(float a, float b, uint& hi, uint& lo) {
    uint ua = __builtin_bit_cast(uint, a), ub = __builtin_bit_cast(uint, b);
    hi = (ua >> 16) | (ub & 0xffff0000u);
    float ra = a - __builtin_bit_cast(float, ua & 0xffff0000u);
    float rb = b - __builtin_bit_cast(float, ub & 0xffff0000u);
    lo = (uint)bf16_rtne(ra) | ((uint)bf16_rtne(rb) << 16);
}

// ---------------------------------------------------------------------------
// Weight transpose + bf16 split: src[K][N] fp32 -> dstH/dstL[N][K] bf16.
// (validated round 4)
// ---------------------------------------------------------------------------
__global__ __launch_bounds__(256) void wsplit_kernel(const float* __restrict__ src,
                                                     ushort* __restrict__ dstH,
                                                     ushort* __restrict__ dstL,
                                                     int K, int N, size_t zstride) {
    __shared__ float T[64][65];
    src += (size_t)blockIdx.z * zstride;
    dstH += (size_t)blockIdx.z * zstride;
    dstL += (size_t)blockIdx.z * zstride;
    const int t = threadIdx.x;
    const int n0 = blockIdx.x * 64;
    const int k0 = blockIdx.y * 64;
    {
        const int kr = t >> 4, nc = (t & 15) * 4;
#pragma unroll
        for (int i = 0; i < 4; ++i) {
            float4 v = *(const float4*)&src[(size_t)(k0 + kr + 16 * i) * N + n0 + nc];
            T[kr + 16 * i][nc + 0] = v.x;
            T[kr + 16 * i][nc + 1] = v.y;
            T[kr + 16 * i][nc + 2] = v.z;
            T[kr + 16 * i][nc + 3] = v.w;
        }
    }
    __syncthreads();
    const int n = t >> 2;
    const int kc = (t & 3) * 16;
    uint h[8], l[8];
#pragma unroll
    for (int i = 0; i < 8; ++i)
        split2(T[kc + 2 * i][n], T[kc + 2 * i + 1][n], h[i], l[i]);
    ushort* dh = &dstH[(size_t)(n0 + n) * K + k0 + kc];
    ushort* dl = &dstL[(size_t)(n0 + n) * K + k0 + kc];
    *(uint4*)(dh + 0) = uint4{h[0], h[1], h[2], h[3]};
    *(uint4*)(dh + 8) = uint4{h[4], h[5], h[6], h[7]};
    *(uint4*)(dl + 0) = uint4{l[0], l[1], l[2], l[3]};
    *(uint4*)(dl + 8) = uint4{l[4], l[5], l[6], l[7]};
}

// ---------------------------------------------------------------------------
// Split-bf16 (bf16x3) MFMA GEMM (validated round 4 — UNCHANGED)
// ---------------------------------------------------------------------------
template <int BM, int BN, bool RELU>
__global__ __launch_bounds__(256) void gemm_mfma(const float* __restrict__ A0,
                                                 const float* __restrict__ A1,
                                                 const ushort* __restrict__ WTh,
                                                 const ushort* __restrict__ WTl,
                                                 const float* __restrict__ bias,
                                                 float* __restrict__ C,
                                                 int M, int N, int K,
                                                 size_t wz, size_t cz) {
    constexpr int FM = BM / 32;
    constexpr int FN = BN / 32;
    constexpr int EA = BM / 32;
    constexpr int EB = BN / 64;
    constexpr int AROW = 40;

    __shared__ ushort Ah[BM * AROW];
    __shared__ ushort Al[BM * AROW];
    __shared__ ushort Bh[BN * AROW];
    __shared__ ushort Bl[BN * AROW];

    const float* A = (blockIdx.z == 0) ? A0 : A1;
    WTh += (size_t)blockIdx.z * wz;
    WTl += (size_t)blockIdx.z * wz;
    bias += (size_t)blockIdx.z * (size_t)N;
    C += (size_t)blockIdx.z * cz;

    const int tid = threadIdx.x;
    const int lane = tid & 63;
    const int wv = tid >> 6;
    const int wm = wv >> 1, wn = wv & 1;
    const int bm = blockIdx.x * BM;
    const int bn = blockIdx.y * BN;

    const int a_m = tid >> 3;
    const int a_kk = (tid & 7) * 4;
    const int b_n = tid >> 2;
    const int b_kq = (tid & 3) * 8;

    const float* aP[EA];
#pragma unroll
    for (int i = 0; i < EA; ++i)
        aP[i] = A + (size_t)(bm + 32 * i + a_m) * K + a_kk;
    const ushort* bPh[EB];
    const ushort* bPl[EB];
#pragma unroll
    for (int i = 0; i < EB; ++i) {
        const size_t off = (size_t)(bn + 64 * i + b_n) * K + b_kq;
        bPh[i] = WTh + off;
        bPl[i] = WTl + off;
    }

    f32x4 apre[EA];
    uint4 bhpre[EB], blpre[EB];
#pragma unroll
    for (int i = 0; i < EA; ++i) apre[i] = *(const f32x4*)(aP[i]);
#pragma unroll
    for (int i = 0; i < EB; ++i) {
        bhpre[i] = *(const uint4*)(bPh[i]);
        blpre[i] = *(const uint4*)(bPl[i]);
    }

    f32x4 acc[FM][FN] = {};

    const int NT = K >> 5;
    for (int kt = 0; kt < NT; ++kt) {
#pragma unroll
        for (int i = 0; i < EA; ++i) {
            uint h0, l0, h1, l1;
            split2(apre[i][0], apre[i][1], h0, l0);
            split2(apre[i][2], apre[i][3], h1, l1);
            const int idx = (32 * i + a_m) * AROW + a_kk;
            *(uint2*)&Ah[idx] = uint2{h0, h1};
            *(uint2*)&Al[idx] = uint2{l0, l1};
        }
#pragma unroll
        for (int i = 0; i < EB; ++i) {
            const int idx = (64 * i + b_n) * AROW + b_kq;
            *(uint4*)&Bh[idx] = bhpre[i];
            *(uint4*)&Bl[idx] = blpre[i];
        }
        __syncthreads();

        if (kt + 1 < NT) {
            const int ko = (kt + 1) * 32;
#pragma unroll
            for (int i = 0; i < EA; ++i) apre[i] = *(const f32x4*)(aP[i] + ko);
#pragma unroll
            for (int i = 0; i < EB; ++i) {
                bhpre[i] = *(const uint4*)(bPh[i] + ko);
                blpre[i] = *(const uint4*)(bPl[i] + ko);
            }
        }

        const int g8 = (lane >> 4) * 8;
        short8 afh[FM], afl[FM], bfh[FN], bfl[FN];
#pragma unroll
        for (int mi = 0; mi < FM; ++mi) {
            const int o = (wm * (BM / 2) + mi * 16 + (lane & 15)) * AROW + g8;
            afh[mi] = *(const short8*)&Ah[o];
            afl[mi] = *(const short8*)&Al[o];
        }
#pragma unroll
        for (int ni = 0; ni < FN; ++ni) {
            const int o = (wn * (BN / 2) + ni * 16 + (lane & 15)) * AROW + g8;
            bfh[ni] = *(const short8*)&Bh[o];
            bfl[ni] = *(const short8*)&Bl[o];
        }

#pragma unroll
        for (int ni = 0; ni < FN; ++ni)
#pragma unroll
            for (int mi = 0; mi < FM; ++mi) {
                acc[mi][ni] = __builtin_amdgcn_mfma_f32_16x16x32_bf16(afh[mi], bfh[ni], acc[mi][ni], 0, 0, 0);
                acc[mi][ni] = __builtin_amdgcn_mfma_f32_16x16x32_bf16(afh[mi], bfl[ni], acc[mi][ni], 0, 0, 0);
                acc[mi][ni] = __builtin_amdgcn_mfma_f32_16x16x32_bf16(afl[mi], bfh[ni], acc[mi][ni], 0, 0, 0);
            }
        __syncthreads();
    }

#pragma unroll
    for (int ni = 0; ni < FN; ++ni) {
        const int col = bn + wn * (BN / 2) + ni * 16 + (lane & 15);
        const float bv = bias[col];
#pragma unroll
        for (int mi = 0; mi < FM; ++mi) {
            const int r0 = bm + wm * (BM / 2) + mi * 16 + (lane >> 4) * 4;
#pragma unroll
            for (int r = 0; r < 4; ++r) {
                float v = acc[mi][ni][r] + bv;
                if (RELU) v = fmaxf(v, 0.0f);
                C[(size_t)(r0 + r) * N + col] = v;
            }
        }
    }
}

// ---------------------------------------------------------------------------
// MFMA flash attention. One block = 256 thr = 4 waves; wave owns 16 q-rows.
// grid (SEQ/64, BATCH*NH). Q,K,V fp32 [B,S,D], head h at cols h*64..h*64+63.
// Layout facts reused from the VALIDATED gemm_mfma:
//   A/B-frag: lane reads 8 consecutive-k bf16 at [row = lane&15][k = (lane>>4)*8]
//   C/D: col = lane&15, row-reg = (lane>>4)*4 + r
// K staged [key][dh] (contraction dh, natural). V staged [dh][key] (transposed
// during staging; vectorized uint4 writes). P staged bf16 per-wave [q][key]
// with phys-row swizzle 4r+g (distinct bank quads), read back as A-frags.
// Online softmax fp32 in registers; row q lives in one 16-lane group.
// MODE 0: key masked where srctok==PAD; MODE 1: causal | tgttok==PAD.
// ---------------------------------------------------------------------------
template <int MODE>
__global__ __launch_bounds__(256) void attn_mfma(const float* __restrict__ Qm,
                                                 const float* __restrict__ Km,
                                                 const float* __restrict__ Vm,
                                                 const int* __restrict__ toks,
                                                 float* __restrict__ Om) {
    constexpr int ROW = 72;              // ushort row stride (144 B, 16B-aligned)
    __shared__ ushort Kl[64 * ROW];      // [key][dh]
    __shared__ ushort Vl[64 * ROW];      // [dh][key]
    __shared__ ushort Pl[4][16 * ROW];   // per-wave [phys_q][key]

    const int tid = threadIdx.x;
    const int lane = tid & 63;
    const int w = tid >> 6;
    const int g = lane >> 4, c = lane & 15;
    const int b = blockIdx.y >> 3, h = blockIdx.y & 7;
    const int q0 = blockIdx.x * 64;
    const size_t base = (size_t)b * SEQ * D + h * DH;
    const int* tokp = toks + b * SEQ;

    // ---- Q fragments (bf16 rtne): row = q0+16w+c, k(dh) = kc*32 + g*8 + e ----
    short8 qf[2];
    {
        const float* qp = Qm + base + (size_t)(q0 + w * 16 + c) * D + g * 8;
#pragma unroll
        for (int kc = 0; kc < 2; ++kc) {
            union { ushort us[8]; short8 s8; } u;
#pragma unroll
            for (int i = 0; i < 8; ++i) u.us[i] = bf16_rtne(qp[kc * 32 + i]);
            qf[kc] = u.s8;
        }
    }

    // staging maps
    const int sk_key = tid >> 2, sk_dh = (tid & 3) * 16;   // K: [key][dh] rows
    const int sv_dh = tid >> 2, sv_key = (tid & 3) * 16;   // V^T: [dh][key] rows
    const float* kP = Km + base + (size_t)sk_key * D + sk_dh;
    const float* vP = Vm + base + (size_t)sv_key * D + sv_dh;

    f32x4 kreg[4];
    float vreg[16];
#pragma unroll
    for (int j = 0; j < 4; ++j) kreg[j] = *(const f32x4*)(kP + 4 * j);
#pragma unroll
    for (int i = 0; i < 16; ++i) vreg[i] = vP[(size_t)i * D];

    f32x4 Ov[4] = {};                    // O acc [nd]; regs r = q-rows
    float m_r[4], l_r[4];
#pragma unroll
    for (int r = 0; r < 4; ++r) { m_r[r] = -1e30f; l_r[r] = 0.f; }

    for (int kt = 0; kt < SEQ / 64; ++kt) {
        // ---- stage K (natural) and V (transposed) from prefetched regs ----
        {
            union { ushort us[16]; uint4 u4[2]; } uk, uv;
#pragma unroll
            for (int j = 0; j < 4; ++j)
#pragma unroll
                for (int i = 0; i < 4; ++i) uk.us[4 * j + i] = bf16_rtne(kreg[j][i]);
#pragma unroll
            for (int i = 0; i < 16; ++i) uv.us[i] = bf16_rtne(vreg[i]);
            *(uint4*)&Kl[sk_key * ROW + sk_dh + 0] = uk.u4[0];
            *(uint4*)&Kl[sk_key * ROW + sk_dh + 8] = uk.u4[1];
            *(uint4*)&Vl[sv_dh * ROW + sv_key + 0] = uv.u4[0];
            *(uint4*)&Vl[sv_dh * ROW + sv_key + 8] = uv.u4[1];
        }
        __syncthreads();

        // ---- prefetch next tile (global, stays on vmcnt) ----
        if (kt + 1 < SEQ / 64) {
            const size_t adv = (size_t)(kt + 1) * 64 * D;
#pragma unroll
            for (int j = 0; j < 4; ++j) kreg[j] = *(const f32x4*)(kP + adv + 4 * j);
#pragma unroll
            for (int i = 0; i < 16; ++i) vreg[i] = vP[adv + (size_t)i * D];
        }

        // ---- QK^T: sc[ni] regs r = q-rows, col c = key ni*16+c ----
        f32x4 sc[4] = {};
#pragma unroll
        for (int ni = 0; ni < 4; ++ni)
#pragma unroll
            for (int kc = 0; kc < 2; ++kc) {
                short8 kf = *(const short8*)&Kl[(ni * 16 + c) * ROW + kc * 32 + g * 8];
                sc[ni] = __builtin_amdgcn_mfma_f32_16x16x32_bf16(qf[kc], kf, sc[ni], 0, 0, 0);
            }

        // ---- mask + scale; masked = -1e30 sentinel ----
        const int k0g = kt * 64;
        int tk[4];
#pragma unroll
        for (int ni = 0; ni < 4; ++ni) tk[ni] = tokp[k0g + ni * 16 + c];
        float p[4][4], tm[4];
#pragma unroll
        for (int r = 0; r < 4; ++r) tm[r] = -1e30f;
#pragma unroll
        for (int ni = 0; ni < 4; ++ni) {
            const int key = k0g + ni * 16 + c;
            const bool colmask = (tk[ni] == 0);
#pragma unroll
            for (int r = 0; r < 4; ++r) {
                bool msk = colmask;
                if (MODE == 1) msk = msk || (key > q0 + w * 16 + 4 * g + r);
                const float s = msk ? -1e30f : sc[ni][r] * 0.125f;
                p[ni][r] = s;
                tm[r] = fmaxf(tm[r], s);
            }
        }
        // ---- online softmax (16-lane group = one q-row set) ----
#pragma unroll
        for (int off = 1; off < 16; off <<= 1)
#pragma unroll
            for (int r = 0; r < 4; ++r) tm[r] = fmaxf(tm[r], __shfl_xor(tm[r], off, 16));
        float f_r[4], ts[4];
#pragma unroll
        for (int r = 0; r < 4; ++r) {
            const float mn = fmaxf(m_r[r], tm[r]);
            f_r[r] = __expf(m_r[r] - mn);   // m_r=-1e30 first tile -> f=0, O=0 anyway
            m_r[r] = mn;
            ts[r] = 0.f;
        }
#pragma unroll
        for (int ni = 0; ni < 4; ++ni)
#pragma unroll
            for (int r = 0; r < 4; ++r) {
                const float e = (p[ni][r] <= -1e29f) ? 0.f : __expf(p[ni][r] - m_r[r]);
                p[ni][r] = e;
                ts[r] += e;
            }
#pragma unroll
        for (int off = 1; off < 16; off <<= 1)
#pragma unroll
            for (int r = 0; r < 4; ++r) ts[r] += __shfl_xor(ts[r], off, 16);
#pragma unroll
        for (int r = 0; r < 4; ++r) l_r[r] = l_r[r] * f_r[r] + ts[r];
#pragma unroll
        for (int nd = 0; nd < 4; ++nd)
#pragma unroll
            for (int r = 0; r < 4; ++r) Ov[nd][r] *= f_r[r];

        // ---- P -> per-wave LDS (bf16), phys row 4r+g ----
#pragma unroll
        for (int ni = 0; ni < 4; ++ni)
#pragma unroll
            for (int r = 0; r < 4; ++r)
                Pl[w][(4 * r + g) * ROW + ni * 16 + c] = bf16_rtne(p[ni][r]);
        // drain LDS queue before reading P back (rule #18)
        asm volatile("s_waitcnt lgkmcnt(0)" ::: "memory");
        __builtin_amdgcn_sched_barrier(0);

        // ---- PV: O[nd] += P-frag[kc] x V-frag[nd][kc] ----
        const int pr = ((c & 3) << 2) | (c >> 2);   // phys row for q = c
#pragma unroll
        for (int kc = 0; kc < 2; ++kc) {
            short8 pf = *(const short8*)&Pl[w][pr * ROW + kc * 32 + g * 8];
#pragma unroll
            for (int nd = 0; nd < 4; ++nd) {
                short8 vf = *(const short8*)&Vl[(nd * 16 + c) * ROW + kc * 32 + g * 8];
                Ov[nd] = __builtin_amdgcn_mfma_f32_16x16x32_bf16(pf, vf, Ov[nd], 0, 0, 0);
            }
        }
        __syncthreads();
    }

    // ---- epilogue ----
    float inv[4];
#pragma unroll
    for (int r = 0; r < 4; ++r) inv[r] = 1.0f / l_r[r];
    float* op = Om + base;
#pragma unroll
    for (int nd = 0; nd < 4; ++nd)
#pragma unroll
        for (int r = 0; r < 4; ++r)
            op[(size_t)(q0 + w * 16 + 4 * g + r) * D + nd * 16 + c] = Ov[nd][r] * inv[r];
}

// ---------------------------------------------------------------------------
// Embedding + positional encoding (validated round 2)
// ---------------------------------------------------------------------------
__global__ __launch_bounds__(128) void embed_kernel(const int* __restrict__ toks,
                                                    const float* __restrict__ emb,
                                                    float* __restrict__ out) {
    const int row = blockIdx.x;
    const int s = row & (SEQ - 1);
    const int tok = toks[row];
    const int d = threadIdx.x * 4;
    float4 e = *(const float4*)&emb[tok * D + d];
    float r[4];
#pragma unroll
    for (int i = 0; i < 4; i += 2) {
        const int dd = d + i;
        const float dv = expf((float)dd * (-9.210340371976184f / (float)D));
        const float ang = (float)s * dv;
        r[i] = sinf(ang);
        r[i + 1] = cosf(ang);
    }
    float4 o;
    o.x = e.x + r[0]; o.y = e.y + r[1]; o.z = e.z + r[2]; o.w = e.w + r[3];
    *(float4*)&out[row * D + d] = o;
}

// ---------------------------------------------------------------------------
// Residual add + LayerNorm (validated round 2)
// ---------------------------------------------------------------------------
__global__ __launch_bounds__(128) void add_ln_kernel(float* __restrict__ x,
                                                     const float* __restrict__ r,
                                                     const float* __restrict__ g,
                                                     const float* __restrict__ b) {
    const int row = blockIdx.x;
    const int t = threadIdx.x;
    const int d = t * 4;
    float4 xv = *(const float4*)&x[row * D + d];
    float4 rv = *(const float4*)&r[row * D + d];
    float4 v;
    v.x = xv.x + rv.x; v.y = xv.y + rv.y; v.z = xv.z + rv.z; v.w = xv.w + rv.w;
    float s = v.x + v.y + v.z + v.w;
    float s2 = v.x * v.x + v.y * v.y + v.z * v.z + v.w * v.w;
#pragma unroll
    for (int off = 32; off > 0; off >>= 1) {
        s += __shfl_down(s, off);
        s2 += __shfl_down(s2, off);
    }
    __shared__ float sh[4];
    if ((t & 63) == 0) { sh[(t >> 6) * 2] = s; sh[(t >> 6) * 2 + 1] = s2; }
    __syncthreads();
    s = sh[0] + sh[2];
    s2 = sh[1] + sh[3];
    const float mean = s * (1.0f / D);
    const float var = s2 * (1.0f / D) - mean * mean;
    const float rstd = rsqrtf(var + LNEPS);
    float4 gv = *(const float4*)&g[d];
    float4 bv = *(const float4*)&b[d];
    float4 o;
    o.x = (v.x - mean) * rstd * gv.x + bv.x;
    o.y = (v.y - mean) * rstd * gv.y + bv.y;
    o.z = (v.z - mean) * rstd * gv.z + bv.z;
    o.w = (v.w - mean) * rstd * gv.w + bv.w;
    *(float4*)&x[row * D + d] = o;
}

// ---------------------------------------------------------------------------
// Host-side orchestration
// ---------------------------------------------------------------------------
extern "C" void kernel_launch(void* const* d_in, const int* in_sizes, int n_in,
                              void* d_out, int out_size, void* d_ws, size_t ws_size,
                              hipStream_t stream) {
    const int* src = (const int*)d_in[0];
    const int* tgt = (const int*)d_in[1];
    const float* emb_src = (const float*)d_in[2];
    const float* emb_tgt = (const float*)d_in[3];
    const float* enc_attn_w = (const float*)d_in[4];
    const float* enc_attn_b = (const float*)d_in[5];
    const float* enc_ff_w1 = (const float*)d_in[6];
    const float* enc_ff_b1 = (const float*)d_in[7];
    const float* enc_ff_w2 = (const float*)d_in[8];
    const float* enc_ff_b2 = (const float*)d_in[9];
    const float* enc_ln_g = (const float*)d_in[10];
    const float* enc_ln_b = (const float*)d_in[11];
    const float* dec_attn_w = (const float*)d_in[12];
    const float* dec_attn_b = (const float*)d_in[13];
    const float* dec_ff_w1 = (const float*)d_in[14];
    const float* dec_ff_b1 = (const float*)d_in[15];
    const float* dec_ff_w2 = (const float*)d_in[16];
    const float* dec_ff_b2 = (const float*)d_in[17];
    const float* dec_ln_g = (const float*)d_in[18];
    const float* dec_ln_b = (const float*)d_in[19];
    const float* fc_w = (const float*)d_in[20];
    const float* fc_b = (const float*)d_in[21];
    float* out = (float*)d_out;

    float* ws = (float*)d_ws;
    const size_t NTOK = (size_t)MROWS * D;   // 1M floats
    float* xe = ws;
    float* xd = xe + NTOK;
    float* qb = xd + NTOK;        // qb,kb,vb contiguous (z-batched QKV)
    float* kb = qb + NTOK;
    float* vb = kb + NTOK;
    float* ab = vb + NTOK;
    float* tb = ab + NTOK;
    float* hb = tb + NTOK;        // 4M floats
    ushort* u0 = (ushort*)(hb + (size_t)MROWS * HID);
    const size_t DD = (size_t)D * D;
    ushort* wAh = u0;
    ushort* wAl = wAh + 8 * DD;
    ushort* wF1h = wAl + 8 * DD;
    ushort* wF1l = wF1h + DD * 4;
    ushort* wF2h = wF1l + DD * 4;
    ushort* wF2l = wF2h + DD * 4;
    ushort* wFCh = wF2l + DD * 4;
    ushort* wFCl = wFCh + (size_t)D * NVT;

    auto transpose = [&](const float* w, ushort* dh, ushort* dl, int K, int N, int nz) {
        dim3 grid(N / 64, K / 64, nz);
        wsplit_kernel<<<grid, 256, 0, stream>>>(w, dh, dl, K, N, (size_t)K * N);
    };
    auto gemm64 = [&](const float* A, const ushort* WTh, const ushort* WTl,
                      const float* bias, float* C, int M, int N, int K) {
        dim3 grid(M / 64, N / 64, 1);
        gemm_mfma<64, 64, false><<<grid, 256, 0, stream>>>(A, A, WTh, WTl, bias, C, M, N, K, 0, 0);
    };
    auto gemm128 = [&](const float* A, const ushort* WTh, const ushort* WTl,
                       const float* bias, float* C, int M, int N, int K, bool relu) {
        dim3 grid(M / 128, N / 128, 1);
        if (relu)
            gemm_mfma<128, 128, true><<<grid, 256, 0, stream>>>(A, A, WTh, WTl, bias, C, M, N, K, 0, 0);
        else
            gemm_mfma<128, 128, false><<<grid, 256, 0, stream>>>(A, A, WTh, WTl, bias, C, M, N, K, 0, 0);
    };
    auto gemm_qkv = [&](const float* Aq, const float* Akv,
                        const ushort* WTh, const ushort* WTl, const float* bi) {
        dim3 grid(MROWS / 128, D / 128, 3);
        gemm_mfma<128, 128, false><<<grid, 256, 0, stream>>>(Aq, Akv, WTh, WTl, bi, qb,
                                                             MROWS, D, D, DD, NTOK);
    };

    embed_kernel<<<MROWS, 128, 0, stream>>>(src, emb_src, xe);
    embed_kernel<<<MROWS, 128, 0, stream>>>(tgt, emb_tgt, xd);

    const dim3 attn_grid(SEQ / 64, BATCH * NH);

    // ---------------- encoder ----------------
    for (int l = 0; l < NL; ++l) {
        const float* bi = enc_attn_b + (size_t)l * 4 * D;
        transpose(enc_attn_w + (size_t)l * 4 * DD, wAh, wAl, D, D, 4);
        transpose(enc_ff_w1 + (size_t)l * D * HID, wF1h, wF1l, D, HID, 1);
        transpose(enc_ff_w2 + (size_t)l * HID * D, wF2h, wF2l, HID, D, 1);

        gemm_qkv(xe, xe, wAh, wAl, bi);
        attn_mfma<0><<<attn_grid, 256, 0, stream>>>(qb, kb, vb, src, ab);
        gemm64(ab, wAh + 3 * DD, wAl + 3 * DD, bi + 3 * D, tb, MROWS, D, D);
        add_ln_kernel<<<MROWS, 128, 0, stream>>>(xe, tb,
            enc_ln_g + (size_t)(l * 2 + 0) * D, enc_ln_b + (size_t)(l * 2 + 0) * D);
        gemm128(xe, wF1h, wF1l, enc_ff_b1 + (size_t)l * HID, hb, MROWS, HID, D, true);
        gemm64(hb, wF2h, wF2l, enc_ff_b2 + (size_t)l * D, tb, MROWS, D, HID);
        add_ln_kernel<<<MROWS, 128, 0, stream>>>(xe, tb,
            enc_ln_g + (size_t)(l * 2 + 1) * D, enc_ln_b + (size_t)(l * 2 + 1) * D);
    }

    // ---------------- decoder ----------------
    for (int l = 0; l < NL; ++l) {
        transpose(dec_attn_w + (size_t)l * 8 * DD, wAh, wAl, D, D, 8);
        transpose(dec_ff_w1 + (size_t)l * D * HID, wF1h, wF1l, D, HID, 1);
        transpose(dec_ff_w2 + (size_t)l * HID * D, wF2h, wF2l, HID, D, 1);
        {   // self-attention (causal + tgt pad mask): slabs 0-3
            const float* bi = dec_attn_b + (size_t)(l * 2 + 0) * 4 * D;
            gemm_qkv(xd, xd, wAh, wAl, bi);
            attn_mfma<1><<<attn_grid, 256, 0, stream>>>(qb, kb, vb, tgt, ab);
            gemm64(ab, wAh + 3 * DD, wAl + 3 * DD, bi + 3 * D, tb, MROWS, D, D);
            add_ln_kernel<<<MROWS, 128, 0, stream>>>(xd, tb,
                dec_ln_g + (size_t)(l * 3 + 0) * D, dec_ln_b + (size_t)(l * 3 + 0) * D);
        }
        {   // cross-attention: Q from xd, K/V from xe: slabs 4-7
            const float* bi = dec_attn_b + (size_t)(l * 2 + 1) * 4 * D;
            gemm_qkv(xd, xe, wAh + 4 * DD, wAl + 4 * DD, bi);
            attn_mfma<0><<<attn_grid, 256, 0, stream>>>(qb, kb, vb, src, ab);
            gemm64(ab, wAh + 7 * DD, wAl + 7 * DD, bi + 3 * D, tb, MROWS, D, D);
            add_ln_kernel<<<MROWS, 128, 0, stream>>>(xd, tb,
                dec_ln_g + (size_t)(l * 3 + 1) * D, dec_ln_b + (size_t)(l * 3 + 1) * D);
        }
        gemm128(xd, wF1h, wF1l, dec_ff_b1 + (size_t)l * HID, hb, MROWS, HID, D, true);
        gemm64(hb, wF2h, wF2l, dec_ff_b2 + (size_t)l * D, tb, MROWS, D, HID);
        add_ln_kernel<<<MROWS, 128, 0, stream>>>(xd, tb,
            dec_ln_g + (size_t)(l * 3 + 2) * D, dec_ln_b + (size_t)(l * 3 + 2) * D);
    }

    // final projection -> logits [B*T, VT]
    transpose(fc_w, wFCh, wFCl, D, NVT, 1);
    {
        dim3 grid(MROWS / 128, NVT / 128, 1);
        gemm_mfma<128, 128, false><<<grid, 256, 0, stream>>>(xd, xd, wFCh, wFCl, fc_b, out,
                                                             MROWS, NVT, D, 0, 0);
    }
}

// Round 6
// 2335.690 us; speedup vs baseline: 2.6874x; 1.2292x over previous
//
#include <hip/hip_runtime.h>
#include <math.h>

#define D 512
#define NH 8
#define DH 64
#define HID 2048
#define NL 6
#define SEQ 512
#define BATCH 4
#define MROWS (BATCH * SEQ)   // 2048
#define NVT 16000
#define LNEPS 1e-5f

typedef __attribute__((ext_vector_type(8))) short short8;
typedef __attribute__((ext_vector_type(4))) float f32x4;

// ---------------------------------------------------------------------------
// bf16 RTNE helpers (single-plane bf16x1 this round; x3 was 3x margin unused)
// ---------------------------------------------------------------------------
__device__ __forceinline__ ushort bf16_rtne(float f) {
    uint u = __builtin_bit_cast(uint, f);
    return (ushort)((u + 0x7fffu + ((u >> 16) & 1u)) >> 16);
}
__device__ __forceinline__ uint rtne2(float a, float b) {
    return (uint)bf16_rtne(a) | ((uint)bf16_rtne(b) << 16);
}

// ---------------------------------------------------------------------------
// Weight transpose + bf16 convert: src[K][N] fp32 -> dst[N][K] bf16 (rtne).
// 64x64 tiles via LDS [64][65].
// ---------------------------------------------------------------------------
__global__ __launch_bounds__(256) void wsplit_kernel(const float* __restrict__ src,
                                                     ushort* __restrict__ dst,
                                                     int K, int N, size_t zstride) {
    __shared__ float T[64][65];
    src += (size_t)blockIdx.z * zstride;
    dst += (size_t)blockIdx.z * zstride;
    const int t = threadIdx.x;
    const int n0 = blockIdx.x * 64;
    const int k0 = blockIdx.y * 64;
    {
        const int kr = t >> 4, nc = (t & 15) * 4;
#pragma unroll
        for (int i = 0; i < 4; ++i) {
            float4 v = *(const float4*)&src[(size_t)(k0 + kr + 16 * i) * N + n0 + nc];
            T[kr + 16 * i][nc + 0] = v.x;
            T[kr + 16 * i][nc + 1] = v.y;
            T[kr + 16 * i][nc + 2] = v.z;
            T[kr + 16 * i][nc + 3] = v.w;
        }
    }
    __syncthreads();
    const int n = t >> 2;
    const int kc = (t & 3) * 16;
    uint h[8];
#pragma unroll
    for (int i = 0; i < 8; ++i)
        h[i] = rtne2(T[kc + 2 * i][n], T[kc + 2 * i + 1][n]);
    ushort* dh = &dst[(size_t)(n0 + n) * K + k0 + kc];
    *(uint4*)(dh + 0) = uint4{h[0], h[1], h[2], h[3]};
    *(uint4*)(dh + 8) = uint4{h[4], h[5], h[6], h[7]};
}

// ---------------------------------------------------------------------------
// bf16 MFMA GEMM: C[M,N] = A[M,K] @ W[K,N] + bias, opt ReLU.
// A fp32 (rtne-converted during staging); W pre-transposed bf16 [N][K].
// Identity consecutive-k LDS rows on BOTH operands (validated round 4:
// hardware k-permutation cancels). Fragment = 1 ds_read_b128 of 8 consecutive
// bf16 at [row][8*(lane>>4)], rows padded to 40 ushort / 80 B.
// BK=32, 256 threads = 4 waves (2x2), wave tile (BM/2)x(BN/2), 16x16x32 MFMA.
// grid (M/BM, N/BN, z): m-major. z-batch: W/bias/C slices; A = z ? A1 : A0.
// ---------------------------------------------------------------------------
template <int BM, int BN, bool RELU>
__global__ __launch_bounds__(256) void gemm_mfma(const float* __restrict__ A0,
                                                 const float* __restrict__ A1,
                                                 const ushort* __restrict__ WT,
                                                 const float* __restrict__ bias,
                                                 float* __restrict__ C,
                                                 int M, int N, int K,
                                                 size_t wz, size_t cz) {
    constexpr int FM = BM / 32;
    constexpr int FN = BN / 32;
    constexpr int EA = BM / 32;
    constexpr int EB = BN / 64;
    constexpr int AROW = 40;

    __shared__ ushort Ah[BM * AROW];
    __shared__ ushort Bh[BN * AROW];

    const float* A = (blockIdx.z == 0) ? A0 : A1;
    WT += (size_t)blockIdx.z * wz;
    bias += (size_t)blockIdx.z * (size_t)N;
    C += (size_t)blockIdx.z * cz;

    const int tid = threadIdx.x;
    const int lane = tid & 63;
    const int wv = tid >> 6;
    const int wm = wv >> 1, wn = wv & 1;
    const int bm = blockIdx.x * BM;
    const int bn = blockIdx.y * BN;

    const int a_m = tid >> 3;
    const int a_kk = (tid & 7) * 4;
    const int b_n = tid >> 2;
    const int b_kq = (tid & 3) * 8;

    const float* aP[EA];
#pragma unroll
    for (int i = 0; i < EA; ++i)
        aP[i] = A + (size_t)(bm + 32 * i + a_m) * K + a_kk;
    const ushort* bP[EB];
#pragma unroll
    for (int i = 0; i < EB; ++i)
        bP[i] = WT + (size_t)(bn + 64 * i + b_n) * K + b_kq;

    f32x4 apre[EA];
    uint4 bpre[EB];
#pragma unroll
    for (int i = 0; i < EA; ++i) apre[i] = *(const f32x4*)(aP[i]);
#pragma unroll
    for (int i = 0; i < EB; ++i) bpre[i] = *(const uint4*)(bP[i]);

    f32x4 acc[FM][FN] = {};

    const int NT = K >> 5;
    for (int kt = 0; kt < NT; ++kt) {
        // ---- stage prefetched regs into LDS (rtne convert for A) ----
#pragma unroll
        for (int i = 0; i < EA; ++i) {
            const int idx = (32 * i + a_m) * AROW + a_kk;
            *(uint2*)&Ah[idx] = uint2{rtne2(apre[i][0], apre[i][1]),
                                      rtne2(apre[i][2], apre[i][3])};
        }
#pragma unroll
        for (int i = 0; i < EB; ++i)
            *(uint4*)&Bh[(64 * i + b_n) * AROW + b_kq] = bpre[i];
        __syncthreads();

        // ---- prefetch next k-tile ----
        if (kt + 1 < NT) {
            const int ko = (kt + 1) * 32;
#pragma unroll
            for (int i = 0; i < EA; ++i) apre[i] = *(const f32x4*)(aP[i] + ko);
#pragma unroll
            for (int i = 0; i < EB; ++i) bpre[i] = *(const uint4*)(bP[i] + ko);
        }

        // ---- fragment reads (one b128 each) + MFMA ----
        const int g8 = (lane >> 4) * 8;
        short8 af[FM], bf[FN];
#pragma unroll
        for (int mi = 0; mi < FM; ++mi)
            af[mi] = *(const short8*)&Ah[(wm * (BM / 2) + mi * 16 + (lane & 15)) * AROW + g8];
#pragma unroll
        for (int ni = 0; ni < FN; ++ni)
            bf[ni] = *(const short8*)&Bh[(wn * (BN / 2) + ni * 16 + (lane & 15)) * AROW + g8];

#pragma unroll
        for (int ni = 0; ni < FN; ++ni)
#pragma unroll
            for (int mi = 0; mi < FM; ++mi)
                acc[mi][ni] = __builtin_amdgcn_mfma_f32_16x16x32_bf16(af[mi], bf[ni], acc[mi][ni], 0, 0, 0);
        __syncthreads();
    }

    // ---- epilogue: C/D layout col=lane&15, row=(lane>>4)*4+reg ----
#pragma unroll
    for (int ni = 0; ni < FN; ++ni) {
        const int col = bn + wn * (BN / 2) + ni * 16 + (lane & 15);
        const float bv = bias[col];
#pragma unroll
        for (int mi = 0; mi < FM; ++mi) {
            const int r0 = bm + wm * (BM / 2) + mi * 16 + (lane >> 4) * 4;
#pragma unroll
            for (int r = 0; r < 4; ++r) {
                float v = acc[mi][ni][r] + bv;
                if (RELU) v = fmaxf(v, 0.0f);
                C[(size_t)(r0 + r) * N + col] = v;
            }
        }
    }
}

// ---------------------------------------------------------------------------
// MFMA flash attention (validated round 5 — UNCHANGED)
// ---------------------------------------------------------------------------
template <int MODE>
__global__ __launch_bounds__(256) void attn_mfma(const float* __restrict__ Qm,
                                                 const float* __restrict__ Km,
                                                 const float* __restrict__ Vm,
                                                 const int* __restrict__ toks,
                                                 float* __restrict__ Om) {
    constexpr int ROW = 72;
    __shared__ ushort Kl[64 * ROW];
    __shared__ ushort Vl[64 * ROW];
    __shared__ ushort Pl[4][16 * ROW];

    const int tid = threadIdx.x;
    const int lane = tid & 63;
    const int w = tid >> 6;
    const int g = lane >> 4, c = lane & 15;
    const int b = blockIdx.y >> 3, h = blockIdx.y & 7;
    const int q0 = blockIdx.x * 64;
    const size_t base = (size_t)b * SEQ * D + h * DH;
    const int* tokp = toks + b * SEQ;

    short8 qf[2];
    {
        const float* qp = Qm + base + (size_t)(q0 + w * 16 + c) * D + g * 8;
#pragma unroll
        for (int kc = 0; kc < 2; ++kc) {
            union { ushort us[8]; short8 s8; } u;
#pragma unroll
            for (int i = 0; i < 8; ++i) u.us[i] = bf16_rtne(qp[kc * 32 + i]);
            qf[kc] = u.s8;
        }
    }

    const int sk_key = tid >> 2, sk_dh = (tid & 3) * 16;
    const int sv_dh = tid >> 2, sv_key = (tid & 3) * 16;
    const float* kP = Km + base + (size_t)sk_key * D + sk_dh;
    const float* vP = Vm + base + (size_t)sv_key * D + sv_dh;

    f32x4 kreg[4];
    float vreg[16];
#pragma unroll
    for (int j = 0; j < 4; ++j) kreg[j] = *(const f32x4*)(kP + 4 * j);
#pragma unroll
    for (int i = 0; i < 16; ++i) vreg[i] = vP[(size_t)i * D];

    f32x4 Ov[4] = {};
    float m_r[4], l_r[4];
#pragma unroll
    for (int r = 0; r < 4; ++r) { m_r[r] = -1e30f; l_r[r] = 0.f; }

    for (int kt = 0; kt < SEQ / 64; ++kt) {
        {
            union { ushort us[16]; uint4 u4[2]; } uk, uv;
#pragma unroll
            for (int j = 0; j < 4; ++j)
#pragma unroll
                for (int i = 0; i < 4; ++i) uk.us[4 * j + i] = bf16_rtne(kreg[j][i]);
#pragma unroll
            for (int i = 0; i < 16; ++i) uv.us[i] = bf16_rtne(vreg[i]);
            *(uint4*)&Kl[sk_key * ROW + sk_dh + 0] = uk.u4[0];
            *(uint4*)&Kl[sk_key * ROW + sk_dh + 8] = uk.u4[1];
            *(uint4*)&Vl[sv_dh * ROW + sv_key + 0] = uv.u4[0];
            *(uint4*)&Vl[sv_dh * ROW + sv_key + 8] = uv.u4[1];
        }
        __syncthreads();

        if (kt + 1 < SEQ / 64) {
            const size_t adv = (size_t)(kt + 1) * 64 * D;
#pragma unroll
            for (int j = 0; j < 4; ++j) kreg[j] = *(const f32x4*)(kP + adv + 4 * j);
#pragma unroll
            for (int i = 0; i < 16; ++i) vreg[i] = vP[adv + (size_t)i * D];
        }

        f32x4 sc[4] = {};
#pragma unroll
        for (int ni = 0; ni < 4; ++ni)
#pragma unroll
            for (int kc = 0; kc < 2; ++kc) {
                short8 kf = *(const short8*)&Kl[(ni * 16 + c) * ROW + kc * 32 + g * 8];
                sc[ni] = __builtin_amdgcn_mfma_f32_16x16x32_bf16(qf[kc], kf, sc[ni], 0, 0, 0);
            }

        const int k0g = kt * 64;
        int tk[4];
#pragma unroll
        for (int ni = 0; ni < 4; ++ni) tk[ni] = tokp[k0g + ni * 16 + c];
        float p[4][4], tm[4];
#pragma unroll
        for (int r = 0; r < 4; ++r) tm[r] = -1e30f;
#pragma unroll
        for (int ni = 0; ni < 4; ++ni) {
            const int key = k0g + ni * 16 + c;
            const bool colmask = (tk[ni] == 0);
#pragma unroll
            for (int r = 0; r < 4; ++r) {
                bool msk = colmask;
                if (MODE == 1) msk = msk || (key > q0 + w * 16 + 4 * g + r);
                const float s = msk ? -1e30f : sc[ni][r] * 0.125f;
                p[ni][r] = s;
                tm[r] = fmaxf(tm[r], s);
            }
        }
#pragma unroll
        for (int off = 1; off < 16; off <<= 1)
#pragma unroll
            for (int r = 0; r < 4; ++r) tm[r] = fmaxf(tm[r], __shfl_xor(tm[r], off, 16));
        float f_r[4], ts[4];
#pragma unroll
        for (int r = 0; r < 4; ++r) {
            const float mn = fmaxf(m_r[r], tm[r]);
            f_r[r] = __expf(m_r[r] - mn);
            m_r[r] = mn;
            ts[r] = 0.f;
        }
#pragma unroll
        for (int ni = 0; ni < 4; ++ni)
#pragma unroll
            for (int r = 0; r < 4; ++r) {
                const float e = (p[ni][r] <= -1e29f) ? 0.f : __expf(p[ni][r] - m_r[r]);
                p[ni][r] = e;
                ts[r] += e;
            }
#pragma unroll
        for (int off = 1; off < 16; off <<= 1)
#pragma unroll
            for (int r = 0; r < 4; ++r) ts[r] += __shfl_xor(ts[r], off, 16);
#pragma unroll
        for (int r = 0; r < 4; ++r) l_r[r] = l_r[r] * f_r[r] + ts[r];
#pragma unroll
        for (int nd = 0; nd < 4; ++nd)
#pragma unroll
            for (int r = 0; r < 4; ++r) Ov[nd][r] *= f_r[r];

#pragma unroll
        for (int ni = 0; ni < 4; ++ni)
#pragma unroll
            for (int r = 0; r < 4; ++r)
                Pl[w][(4 * r + g) * ROW + ni * 16 + c] = bf16_rtne(p[ni][r]);
        asm volatile("s_waitcnt lgkmcnt(0)" ::: "memory");
        __builtin_amdgcn_sched_barrier(0);

        const int pr = ((c & 3) << 2) | (c >> 2);
#pragma unroll
        for (int kc = 0; kc < 2; ++kc) {
            short8 pf = *(const short8*)&Pl[w][pr * ROW + kc * 32 + g * 8];
#pragma unroll
            for (int nd = 0; nd < 4; ++nd) {
                short8 vf = *(const short8*)&Vl[(nd * 16 + c) * ROW + kc * 32 + g * 8];
                Ov[nd] = __builtin_amdgcn_mfma_f32_16x16x32_bf16(pf, vf, Ov[nd], 0, 0, 0);
            }
        }
        __syncthreads();
    }

    float inv[4];
#pragma unroll
    for (int r = 0; r < 4; ++r) inv[r] = 1.0f / l_r[r];
    float* op = Om + base;
#pragma unroll
    for (int nd = 0; nd < 4; ++nd)
#pragma unroll
        for (int r = 0; r < 4; ++r)
            op[(size_t)(q0 + w * 16 + 4 * g + r) * D + nd * 16 + c] = Ov[nd][r] * inv[r];
}

// ---------------------------------------------------------------------------
// Embedding + positional encoding (validated round 2)
// ---------------------------------------------------------------------------
__global__ __launch_bounds__(128) void embed_kernel(const int* __restrict__ toks,
                                                    const float* __restrict__ emb,
                                                    float* __restrict__ out) {
    const int row = blockIdx.x;
    const int s = row & (SEQ - 1);
    const int tok = toks[row];
    const int d = threadIdx.x * 4;
    float4 e = *(const float4*)&emb[tok * D + d];
    float r[4];
#pragma unroll
    for (int i = 0; i < 4; i += 2) {
        const int dd = d + i;
        const float dv = expf((float)dd * (-9.210340371976184f / (float)D));
        const float ang = (float)s * dv;
        r[i] = sinf(ang);
        r[i + 1] = cosf(ang);
    }
    float4 o;
    o.x = e.x + r[0]; o.y = e.y + r[1]; o.z = e.z + r[2]; o.w = e.w + r[3];
    *(float4*)&out[row * D + d] = o;
}

// ---------------------------------------------------------------------------
// Residual add + LayerNorm (validated round 2)
// ---------------------------------------------------------------------------
__global__ __launch_bounds__(128) void add_ln_kernel(float* __restrict__ x,
                                                     const float* __restrict__ r,
                                                     const float* __restrict__ g,
                                                     const float* __restrict__ b) {
    const int row = blockIdx.x;
    const int t = threadIdx.x;
    const int d = t * 4;
    float4 xv = *(const float4*)&x[row * D + d];
    float4 rv = *(const float4*)&r[row * D + d];
    float4 v;
    v.x = xv.x + rv.x; v.y = xv.y + rv.y; v.z = xv.z + rv.z; v.w = xv.w + rv.w;
    float s = v.x + v.y + v.z + v.w;
    float s2 = v.x * v.x + v.y * v.y + v.z * v.z + v.w * v.w;
#pragma unroll
    for (int off = 32; off > 0; off >>= 1) {
        s += __shfl_down(s, off);
        s2 += __shfl_down(s2, off);
    }
    __shared__ float sh[4];
    if ((t & 63) == 0) { sh[(t >> 6) * 2] = s; sh[(t >> 6) * 2 + 1] = s2; }
    __syncthreads();
    s = sh[0] + sh[2];
    s2 = sh[1] + sh[3];
    const float mean = s * (1.0f / D);
    const float var = s2 * (1.0f / D) - mean * mean;
    const float rstd = rsqrtf(var + LNEPS);
    float4 gv = *(const float4*)&g[d];
    float4 bv = *(const float4*)&b[d];
    float4 o;
    o.x = (v.x - mean) * rstd * gv.x + bv.x;
    o.y = (v.y - mean) * rstd * gv.y + bv.y;
    o.z = (v.z - mean) * rstd * gv.z + bv.z;
    o.w = (v.w - mean) * rstd * gv.w + bv.w;
    *(float4*)&x[row * D + d] = o;
}

// ---------------------------------------------------------------------------
// Host-side orchestration
// ---------------------------------------------------------------------------
extern "C" void kernel_launch(void* const* d_in, const int* in_sizes, int n_in,
                              void* d_out, int out_size, void* d_ws, size_t ws_size,
                              hipStream_t stream) {
    const int* src = (const int*)d_in[0];
    const int* tgt = (const int*)d_in[1];
    const float* emb_src = (const float*)d_in[2];
    const float* emb_tgt = (const float*)d_in[3];
    const float* enc_attn_w = (const float*)d_in[4];
    const float* enc_attn_b = (const float*)d_in[5];
    const float* enc_ff_w1 = (const float*)d_in[6];
    const float* enc_ff_b1 = (const float*)d_in[7];
    const float* enc_ff_w2 = (const float*)d_in[8];
    const float* enc_ff_b2 = (const float*)d_in[9];
    const float* enc_ln_g = (const float*)d_in[10];
    const float* enc_ln_b = (const float*)d_in[11];
    const float* dec_attn_w = (const float*)d_in[12];
    const float* dec_attn_b = (const float*)d_in[13];
    const float* dec_ff_w1 = (const float*)d_in[14];
    const float* dec_ff_b1 = (const float*)d_in[15];
    const float* dec_ff_w2 = (const float*)d_in[16];
    const float* dec_ff_b2 = (const float*)d_in[17];
    const float* dec_ln_g = (const float*)d_in[18];
    const float* dec_ln_b = (const float*)d_in[19];
    const float* fc_w = (const float*)d_in[20];
    const float* fc_b = (const float*)d_in[21];
    float* out = (float*)d_out;

    float* ws = (float*)d_ws;
    const size_t NTOK = (size_t)MROWS * D;   // 1M floats
    float* xe = ws;
    float* xd = xe + NTOK;
    float* qb = xd + NTOK;        // qb,kb,vb contiguous (z-batched QKV)
    float* kb = qb + NTOK;
    float* vb = kb + NTOK;
    float* ab = vb + NTOK;
    float* tb = ab + NTOK;
    float* hb = tb + NTOK;        // 4M floats
    ushort* u0 = (ushort*)(hb + (size_t)MROWS * HID);
    const size_t DD = (size_t)D * D;
    ushort* wA = u0;                        // 8 * D*D (dec attn worst case)
    ushort* wF1 = wA + 8 * DD;              // D*HID = 4*DD
    ushort* wF2 = wF1 + DD * 4;
    ushort* wFC = wF2 + DD * 4;             // D*NVT

    auto transpose = [&](const float* w, ushort* dh, int K, int N, int nz) {
        dim3 grid(N / 64, K / 64, nz);
        wsplit_kernel<<<grid, 256, 0, stream>>>(w, dh, K, N, (size_t)K * N);
    };
    auto gemm64 = [&](const float* A, const ushort* WT,
                      const float* bias, float* C, int M, int N, int K) {
        dim3 grid(M / 64, N / 64, 1);
        gemm_mfma<64, 64, false><<<grid, 256, 0, stream>>>(A, A, WT, bias, C, M, N, K, 0, 0);
    };
    auto gemm128 = [&](const float* A, const ushort* WT,
                       const float* bias, float* C, int M, int N, int K, bool relu) {
        dim3 grid(M / 128, N / 128, 1);
        if (relu)
            gemm_mfma<128, 128, true><<<grid, 256, 0, stream>>>(A, A, WT, bias, C, M, N, K, 0, 0);
        else
            gemm_mfma<128, 128, false><<<grid, 256, 0, stream>>>(A, A, WT, bias, C, M, N, K, 0, 0);
    };
    auto gemm_qkv = [&](const float* Aq, const float* Akv,
                        const ushort* WT, const float* bi) {
        dim3 grid(MROWS / 128, D / 128, 3);
        gemm_mfma<128, 128, false><<<grid, 256, 0, stream>>>(Aq, Akv, WT, bi, qb,
                                                             MROWS, D, D, DD, NTOK);
    };

    embed_kernel<<<MROWS, 128, 0, stream>>>(src, emb_src, xe);
    embed_kernel<<<MROWS, 128, 0, stream>>>(tgt, emb_tgt, xd);

    const dim3 attn_grid(SEQ / 64, BATCH * NH);

    // ---------------- encoder ----------------
    for (int l = 0; l < NL; ++l) {
        const float* bi = enc_attn_b + (size_t)l * 4 * D;
        transpose(enc_attn_w + (size_t)l * 4 * DD, wA, D, D, 4);
        transpose(enc_ff_w1 + (size_t)l * D * HID, wF1, D, HID, 1);
        transpose(enc_ff_w2 + (size_t)l * HID * D, wF2, HID, D, 1);

        gemm_qkv(xe, xe, wA, bi);
        attn_mfma<0><<<attn_grid, 256, 0, stream>>>(qb, kb, vb, src, ab);
        gemm64(ab, wA + 3 * DD, bi + 3 * D, tb, MROWS, D, D);
        add_ln_kernel<<<MROWS, 128, 0, stream>>>(xe, tb,
            enc_ln_g + (size_t)(l * 2 + 0) * D, enc_ln_b + (size_t)(l * 2 + 0) * D);
        gemm128(xe, wF1, enc_ff_b1 + (size_t)l * HID, hb, MROWS, HID, D, true);
        gemm64(hb, wF2, enc_ff_b2 + (size_t)l * D, tb, MROWS, D, HID);
        add_ln_kernel<<<MROWS, 128, 0, stream>>>(xe, tb,
            enc_ln_g + (size_t)(l * 2 + 1) * D, enc_ln_b + (size_t)(l * 2 + 1) * D);
    }

    // ---------------- decoder ----------------
    for (int l = 0; l < NL; ++l) {
        transpose(dec_attn_w + (size_t)l * 8 * DD, wA, D, D, 8);
        transpose(dec_ff_w1 + (size_t)l * D * HID, wF1, D, HID, 1);
        transpose(dec_ff_w2 + (size_t)l * HID * D, wF2, HID, D, 1);
        {   // self-attention (causal + tgt pad mask): slabs 0-3
            const float* bi = dec_attn_b + (size_t)(l * 2 + 0) * 4 * D;
            gemm_qkv(xd, xd, wA, bi);
            attn_mfma<1><<<attn_grid, 256, 0, stream>>>(qb, kb, vb, tgt, ab);
            gemm64(ab, wA + 3 * DD, bi + 3 * D, tb, MROWS, D, D);
            add_ln_kernel<<<MROWS, 128, 0, stream>>>(xd, tb,
                dec_ln_g + (size_t)(l * 3 + 0) * D, dec_ln_b + (size_t)(l * 3 + 0) * D);
        }
        {   // cross-attention: Q from xd, K/V from xe: slabs 4-7
            const float* bi = dec_attn_b + (size_t)(l * 2 + 1) * 4 * D;
            gemm_qkv(xd, xe, wA + 4 * DD, bi);
            attn_mfma<0><<<attn_grid, 256, 0, stream>>>(qb, kb, vb, src, ab);
            gemm64(ab, wA + 7 * DD, bi + 3 * D, tb, MROWS, D, D);
            add_ln_kernel<<<MROWS, 128, 0, stream>>>(xd, tb,
                dec_ln_g + (size_t)(l * 3 + 1) * D, dec_ln_b + (size_t)(l * 3 + 1) * D);
        }
        gemm128(xd, wF1, dec_ff_b1 + (size_t)l * HID, hb, MROWS, HID, D, true);
        gemm64(hb, wF2, dec_ff_b2 + (size_t)l * D, tb, MROWS, D, HID);
        add_ln_kernel<<<MROWS, 128, 0, stream>>>(xd, tb,
            dec_ln_g + (size_t)(l * 3 + 2) * D, dec_ln_b + (size_t)(l * 3 + 2) * D);
    }

    // final projection -> logits [B*T, VT]
    transpose(fc_w, wFC, D, NVT, 1);
    {
        dim3 grid(MROWS / 128, NVT / 128, 1);
        gemm_mfma<128, 128, false><<<grid, 256, 0, stream>>>(xd, xd, wFC, fc_b, out,
                                                             MROWS, NVT, D, 0, 0);
    }
}

// Round 8
// 2038.889 us; speedup vs baseline: 3.0786x; 1.1456x over previous
//
#include <hip/hip_runtime.h>
#include <math.h>

#define D 512
#define NH 8
#define DH 64
#define HID 2048
#define NL 6
#define SEQ 512
#define BATCH 4
#define MROWS (BATCH * SEQ)   // 2048
#define NVT 16000
#define LNEPS 1e-5f

typedef __attribute__((ext_vector_type(8))) short short8;
typedef __attribute__((ext_vector_type(4))) float f32x4;

// ---------------------------------------------------------------------------
// bf16 RTNE helpers
// ---------------------------------------------------------------------------
__device__ __forceinline__ ushort bf16_rtne(float f) {
    uint u = __builtin_bit_cast(uint, f);
    return (ushort)((u + 0x7fffu + ((u >> 16) & 1u)) >> 16);
}
__device__ __forceinline__ uint rtne2(float a, float b) {
    return (uint)bf16_rtne(a) | ((uint)bf16_rtne(b) << 16);
}

// ---------------------------------------------------------------------------
// Weight transpose + bf16 convert: src[K][N] fp32 -> dst[N][K] bf16 (rtne).
// 64x64 tiles via LDS [64][65]. z batches over zstride (validated round 6).
// ---------------------------------------------------------------------------
__global__ __launch_bounds__(256) void wsplit_kernel(const float* __restrict__ src,
                                                     ushort* __restrict__ dst,
                                                     int K, int N, size_t zstride) {
    __shared__ float T[64][65];
    src += (size_t)blockIdx.z * zstride;
    dst += (size_t)blockIdx.z * zstride;
    const int t = threadIdx.x;
    const int n0 = blockIdx.x * 64;
    const int k0 = blockIdx.y * 64;
    {
        const int kr = t >> 4, nc = (t & 15) * 4;
#pragma unroll
        for (int i = 0; i < 4; ++i) {
            float4 v = *(const float4*)&src[(size_t)(k0 + kr + 16 * i) * N + n0 + nc];
            T[kr + 16 * i][nc + 0] = v.x;
            T[kr + 16 * i][nc + 1] = v.y;
            T[kr + 16 * i][nc + 2] = v.z;
            T[kr + 16 * i][nc + 3] = v.w;
        }
    }
    __syncthreads();
    const int n = t >> 2;
    const int kc = (t & 3) * 16;
    uint h[8];
#pragma unroll
    for (int i = 0; i < 8; ++i)
        h[i] = rtne2(T[kc + 2 * i][n], T[kc + 2 * i + 1][n]);
    ushort* dh = &dst[(size_t)(n0 + n) * K + k0 + kc];
    *(uint4*)(dh + 0) = uint4{h[0], h[1], h[2], h[3]};
    *(uint4*)(dh + 8) = uint4{h[4], h[5], h[6], h[7]};
}

// ---------------------------------------------------------------------------
// bf16 MFMA GEMM, single-barrier double-buffered LDS.
// C[M,N] = A[M,K] @ W[K,N] + bias, opt ReLU. A fp32 (rtne during staging);
// W pre-transposed bf16 [N][K]. Identity consecutive-k rows on both operands
// (validated round 4). Fragment = 1 ds_read_b128 at [row][8*(lane>>4)],
// rows padded to 40 ushort / 80 B.
// Pipeline (1 barrier/iter): iter t reads buf[t&1]; after MFMA, stage tile
// t+1 into buf[t&1 ^ 1] (no reader conflict), issue loads for t+2, sync.
// BK=32, 256 thr = 4 waves (2x2), wave tile (BM/2)x(BN/2), 16x16x32 MFMA.
// grid (M/BM, N/BN, z): m-major. z-batch: W/bias/C slices; A = z ? A1 : A0.
// ---------------------------------------------------------------------------
template <int BM, int BN, bool RELU>
__global__ __launch_bounds__(256) void gemm_mfma(const float* __restrict__ A0,
                                                 const float* __restrict__ A1,
                                                 const ushort* __restrict__ WT,
                                                 const float* __restrict__ bias,
                                                 float* __restrict__ C,
                                                 int M, int N, int K,
                                                 size_t wz, size_t cz) {
    constexpr int FM = BM / 32;
    constexpr int FN = BN / 32;
    constexpr int EA = BM / 32;
    constexpr int EB = BN / 64;
    constexpr int AROW = 40;

    __shared__ ushort Ah[2][BM * AROW];
    __shared__ ushort Bh[2][BN * AROW];

    const float* A = (blockIdx.z == 0) ? A0 : A1;
    WT += (size_t)blockIdx.z * wz;
    bias += (size_t)blockIdx.z * (size_t)N;
    C += (size_t)blockIdx.z * cz;

    const int tid = threadIdx.x;
    const int lane = tid & 63;
    const int wv = tid >> 6;
    const int wm = wv >> 1, wn = wv & 1;
    const int bm = blockIdx.x * BM;
    const int bn = blockIdx.y * BN;

    const int a_m = tid >> 3;
    const int a_kk = (tid & 7) * 4;
    const int b_n = tid >> 2;
    const int b_kq = (tid & 3) * 8;

    const float* aP[EA];
#pragma unroll
    for (int i = 0; i < EA; ++i)
        aP[i] = A + (size_t)(bm + 32 * i + a_m) * K + a_kk;
    const ushort* bP[EB];
#pragma unroll
    for (int i = 0; i < EB; ++i)
        bP[i] = WT + (size_t)(bn + 64 * i + b_n) * K + b_kq;

    f32x4 apre[EA];
    uint4 bpre[EB];
#pragma unroll
    for (int i = 0; i < EA; ++i) apre[i] = *(const f32x4*)(aP[i]);
#pragma unroll
    for (int i = 0; i < EB; ++i) bpre[i] = *(const uint4*)(bP[i]);

    f32x4 acc[FM][FN] = {};
    const int NT = K >> 5;

    // prologue: stage tile 0 into buf 0, issue loads for tile 1
#pragma unroll
    for (int i = 0; i < EA; ++i) {
        const int idx = (32 * i + a_m) * AROW + a_kk;
        *(uint2*)&Ah[0][idx] = uint2{rtne2(apre[i][0], apre[i][1]),
                                     rtne2(apre[i][2], apre[i][3])};
    }
#pragma unroll
    for (int i = 0; i < EB; ++i)
        *(uint4*)&Bh[0][(64 * i + b_n) * AROW + b_kq] = bpre[i];
    if (NT > 1) {
#pragma unroll
        for (int i = 0; i < EA; ++i) apre[i] = *(const f32x4*)(aP[i] + 32);
#pragma unroll
        for (int i = 0; i < EB; ++i) bpre[i] = *(const uint4*)(bP[i] + 32);
    }
    __syncthreads();

    const int g8 = (lane >> 4) * 8;
    for (int t = 0; t < NT; ++t) {
        const int cur = t & 1;
        // ---- fragment reads + MFMA on buf[cur] ----
        short8 af[FM], bf[FN];
#pragma unroll
        for (int mi = 0; mi < FM; ++mi)
            af[mi] = *(const short8*)&Ah[cur][(wm * (BM / 2) + mi * 16 + (lane & 15)) * AROW + g8];
#pragma unroll
        for (int ni = 0; ni < FN; ++ni)
            bf[ni] = *(const short8*)&Bh[cur][(wn * (BN / 2) + ni * 16 + (lane & 15)) * AROW + g8];
#pragma unroll
        for (int ni = 0; ni < FN; ++ni)
#pragma unroll
            for (int mi = 0; mi < FM; ++mi)
                acc[mi][ni] = __builtin_amdgcn_mfma_f32_16x16x32_bf16(af[mi], bf[ni], acc[mi][ni], 0, 0, 0);

        // ---- stage tile t+1 into buf[cur^1]; issue loads for t+2 ----
        if (t + 1 < NT) {
#pragma unroll
            for (int i = 0; i < EA; ++i) {
                const int idx = (32 * i + a_m) * AROW + a_kk;
                *(uint2*)&Ah[cur ^ 1][idx] = uint2{rtne2(apre[i][0], apre[i][1]),
                                                   rtne2(apre[i][2], apre[i][3])};
            }
#pragma unroll
            for (int i = 0; i < EB; ++i)
                *(uint4*)&Bh[cur ^ 1][(64 * i + b_n) * AROW + b_kq] = bpre[i];
            if (t + 2 < NT) {
                const int ko = (t + 2) * 32;
#pragma unroll
                for (int i = 0; i < EA; ++i) apre[i] = *(const f32x4*)(aP[i] + ko);
#pragma unroll
                for (int i = 0; i < EB; ++i) bpre[i] = *(const uint4*)(bP[i] + ko);
            }
        }
        __syncthreads();
    }

    // ---- epilogue: C/D layout col=lane&15, row=(lane>>4)*4+reg ----
#pragma unroll
    for (int ni = 0; ni < FN; ++ni) {
        const int col = bn + wn * (BN / 2) + ni * 16 + (lane & 15);
        const float bv = bias[col];
#pragma unroll
        for (int mi = 0; mi < FM; ++mi) {
            const int r0 = bm + wm * (BM / 2) + mi * 16 + (lane >> 4) * 4;
#pragma unroll
            for (int r = 0; r < 4; ++r) {
                float v = acc[mi][ni][r] + bv;
                if (RELU) v = fmaxf(v, 0.0f);
                C[(size_t)(r0 + r) * N + col] = v;
            }
        }
    }
}

// ---------------------------------------------------------------------------
// MFMA flash attention (validated round 5 — UNCHANGED)
// ---------------------------------------------------------------------------
template <int MODE>
__global__ __launch_bounds__(256) void attn_mfma(const float* __restrict__ Qm,
                                                 const float* __restrict__ Km,
                                                 const float* __restrict__ Vm,
                                                 const int* __restrict__ toks,
                                                 float* __restrict__ Om) {
    constexpr int ROW = 72;
    __shared__ ushort Kl[64 * ROW];
    __shared__ ushort Vl[64 * ROW];
    __shared__ ushort Pl[4][16 * ROW];

    const int tid = threadIdx.x;
    const int lane = tid & 63;
    const int w = tid >> 6;
    const int g = lane >> 4, c = lane & 15;
    const int b = blockIdx.y >> 3, h = blockIdx.y & 7;
    const int q0 = blockIdx.x * 64;
    const size_t base = (size_t)b * SEQ * D + h * DH;
    const int* tokp = toks + b * SEQ;

    short8 qf[2];
    {
        const float* qp = Qm + base + (size_t)(q0 + w * 16 + c) * D + g * 8;
#pragma unroll
        for (int kc = 0; kc < 2; ++kc) {
            union { ushort us[8]; short8 s8; } u;
#pragma unroll
            for (int i = 0; i < 8; ++i) u.us[i] = bf16_rtne(qp[kc * 32 + i]);
            qf[kc] = u.s8;
        }
    }

    const int sk_key = tid >> 2, sk_dh = (tid & 3) * 16;
    const int sv_dh = tid >> 2, sv_key = (tid & 3) * 16;
    const float* kP = Km + base + (size_t)sk_key * D + sk_dh;
    const float* vP = Vm + base + (size_t)sv_key * D + sv_dh;

    f32x4 kreg[4];
    float vreg[16];
#pragma unroll
    for (int j = 0; j < 4; ++j) kreg[j] = *(const f32x4*)(kP + 4 * j);
#pragma unroll
    for (int i = 0; i < 16; ++i) vreg[i] = vP[(size_t)i * D];

    f32x4 Ov[4] = {};
    float m_r[4], l_r[4];
#pragma unroll
    for (int r = 0; r < 4; ++r) { m_r[r] = -1e30f; l_r[r] = 0.f; }

    for (int kt = 0; kt < SEQ / 64; ++kt) {
        {
            union { ushort us[16]; uint4 u4[2]; } uk, uv;
#pragma unroll
            for (int j = 0; j < 4; ++j)
#pragma unroll
                for (int i = 0; i < 4; ++i) uk.us[4 * j + i] = bf16_rtne(kreg[j][i]);
#pragma unroll
            for (int i = 0; i < 16; ++i) uv.us[i] = bf16_rtne(vreg[i]);
            *(uint4*)&Kl[sk_key * ROW + sk_dh + 0] = uk.u4[0];
            *(uint4*)&Kl[sk_key * ROW + sk_dh + 8] = uk.u4[1];
            *(uint4*)&Vl[sv_dh * ROW + sv_key + 0] = uv.u4[0];
            *(uint4*)&Vl[sv_dh * ROW + sv_key + 8] = uv.u4[1];
        }
        __syncthreads();

        if (kt + 1 < SEQ / 64) {
            const size_t adv = (size_t)(kt + 1) * 64 * D;
#pragma unroll
            for (int j = 0; j < 4; ++j) kreg[j] = *(const f32x4*)(kP + adv + 4 * j);
#pragma unroll
            for (int i = 0; i < 16; ++i) vreg[i] = vP[adv + (size_t)i * D];
        }

        f32x4 sc[4] = {};
#pragma unroll
        for (int ni = 0; ni < 4; ++ni)
#pragma unroll
            for (int kc = 0; kc < 2; ++kc) {
                short8 kf = *(const short8*)&Kl[(ni * 16 + c) * ROW + kc * 32 + g * 8];
                sc[ni] = __builtin_amdgcn_mfma_f32_16x16x32_bf16(qf[kc], kf, sc[ni], 0, 0, 0);
            }

        const int k0g = kt * 64;
        int tk[4];
#pragma unroll
        for (int ni = 0; ni < 4; ++ni) tk[ni] = tokp[k0g + ni * 16 + c];
        float p[4][4], tm[4];
#pragma unroll
        for (int r = 0; r < 4; ++r) tm[r] = -1e30f;
#pragma unroll
        for (int ni = 0; ni < 4; ++ni) {
            const int key = k0g + ni * 16 + c;
            const bool colmask = (tk[ni] == 0);
#pragma unroll
            for (int r = 0; r < 4; ++r) {
                bool msk = colmask;
                if (MODE == 1) msk = msk || (key > q0 + w * 16 + 4 * g + r);
                const float s = msk ? -1e30f : sc[ni][r] * 0.125f;
                p[ni][r] = s;
                tm[r] = fmaxf(tm[r], s);
            }
        }
#pragma unroll
        for (int off = 1; off < 16; off <<= 1)
#pragma unroll
            for (int r = 0; r < 4; ++r) tm[r] = fmaxf(tm[r], __shfl_xor(tm[r], off, 16));
        float f_r[4], ts[4];
#pragma unroll
        for (int r = 0; r < 4; ++r) {
            const float mn = fmaxf(m_r[r], tm[r]);
            f_r[r] = __expf(m_r[r] - mn);
            m_r[r] = mn;
            ts[r] = 0.f;
        }
#pragma unroll
        for (int ni = 0; ni < 4; ++ni)
#pragma unroll
            for (int r = 0; r < 4; ++r) {
                const float e = (p[ni][r] <= -1e29f) ? 0.f : __expf(p[ni][r] - m_r[r]);
                p[ni][r] = e;
                ts[r] += e;
            }
#pragma unroll
        for (int off = 1; off < 16; off <<= 1)
#pragma unroll
            for (int r = 0; r < 4; ++r) ts[r] += __shfl_xor(ts[r], off, 16);
#pragma unroll
        for (int r = 0; r < 4; ++r) l_r[r] = l_r[r] * f_r[r] + ts[r];
#pragma unroll
        for (int nd = 0; nd < 4; ++nd)
#pragma unroll
            for (int r = 0; r < 4; ++r) Ov[nd][r] *= f_r[r];

#pragma unroll
        for (int ni = 0; ni < 4; ++ni)
#pragma unroll
            for (int r = 0; r < 4; ++r)
                Pl[w][(4 * r + g) * ROW + ni * 16 + c] = bf16_rtne(p[ni][r]);
        asm volatile("s_waitcnt lgkmcnt(0)" ::: "memory");
        __builtin_amdgcn_sched_barrier(0);

        const int pr = ((c & 3) << 2) | (c >> 2);
#pragma unroll
        for (int kc = 0; kc < 2; ++kc) {
            short8 pf = *(const short8*)&Pl[w][pr * ROW + kc * 32 + g * 8];
#pragma unroll
            for (int nd = 0; nd < 4; ++nd) {
                short8 vf = *(const short8*)&Vl[(nd * 16 + c) * ROW + kc * 32 + g * 8];
                Ov[nd] = __builtin_amdgcn_mfma_f32_16x16x32_bf16(pf, vf, Ov[nd], 0, 0, 0);
            }
        }
        __syncthreads();
    }

    float inv[4];
#pragma unroll
    for (int r = 0; r < 4; ++r) inv[r] = 1.0f / l_r[r];
    float* op = Om + base;
#pragma unroll
    for (int nd = 0; nd < 4; ++nd)
#pragma unroll
        for (int r = 0; r < 4; ++r)
            op[(size_t)(q0 + w * 16 + 4 * g + r) * D + nd * 16 + c] = Ov[nd][r] * inv[r];
}

// ---------------------------------------------------------------------------
// Embedding + positional encoding, both sequences in one dispatch (y selects)
// ---------------------------------------------------------------------------
__global__ __launch_bounds__(128) void embed2_kernel(const int* __restrict__ src,
                                                     const int* __restrict__ tgt,
                                                     const float* __restrict__ es,
                                                     const float* __restrict__ et,
                                                     float* __restrict__ xe,
                                                     float* __restrict__ xd) {
    const int which = blockIdx.y;
    const int* toks = which ? tgt : src;
    const float* emb = which ? et : es;
    float* out = which ? xd : xe;
    const int row = blockIdx.x;
    const int s = row & (SEQ - 1);
    const int tok = toks[row];
    const int d = threadIdx.x * 4;
    float4 e = *(const float4*)&emb[tok * D + d];
    float r[4];
#pragma unroll
    for (int i = 0; i < 4; i += 2) {
        const int dd = d + i;
        const float dv = expf((float)dd * (-9.210340371976184f / (float)D));
        const float ang = (float)s * dv;
        r[i] = sinf(ang);
        r[i + 1] = cosf(ang);
    }
    float4 o;
    o.x = e.x + r[0]; o.y = e.y + r[1]; o.z = e.z + r[2]; o.w = e.w + r[3];
    *(float4*)&out[row * D + d] = o;
}

// ---------------------------------------------------------------------------
// Residual add + LayerNorm (validated round 2 — UNCHANGED)
// ---------------------------------------------------------------------------
__global__ __launch_bounds__(128) void add_ln_kernel(float* __restrict__ x,
                                                     const float* __restrict__ r,
                                                     const float* __restrict__ g,
                                                     const float* __restrict__ b) {
    const int row = blockIdx.x;
    const int t = threadIdx.x;
    const int d = t * 4;
    float4 xv = *(const float4*)&x[row * D + d];
    float4 rv = *(const float4*)&r[row * D + d];
    float4 v;
    v.x = xv.x + rv.x; v.y = xv.y + rv.y; v.z = xv.z + rv.z; v.w = xv.w + rv.w;
    float s = v.x + v.y + v.z + v.w;
    float s2 = v.x * v.x + v.y * v.y + v.z * v.z + v.w * v.w;
#pragma unroll
    for (int off = 32; off > 0; off >>= 1) {
        s += __shfl_down(s, off);
        s2 += __shfl_down(s2, off);
    }
    __shared__ float sh[4];
    if ((t & 63) == 0) { sh[(t >> 6) * 2] = s; sh[(t >> 6) * 2 + 1] = s2; }
    __syncthreads();
    s = sh[0] + sh[2];
    s2 = sh[1] + sh[3];
    const float mean = s * (1.0f / D);
    const float var = s2 * (1.0f / D) - mean * mean;
    const float rstd = rsqrtf(var + LNEPS);
    float4 gv = *(const float4*)&g[d];
    float4 bv = *(const float4*)&b[d];
    float4 o;
    o.x = (v.x - mean) * rstd * gv.x + bv.x;
    o.y = (v.y - mean) * rstd * gv.y + bv.y;
    o.z = (v.z - mean) * rstd * gv.z + bv.z;
    o.w = (v.w - mean) * rstd * gv.w + bv.w;
    *(float4*)&x[row * D + d] = o;
}

// ---------------------------------------------------------------------------
// Host-side orchestration
// ---------------------------------------------------------------------------
extern "C" void kernel_launch(void* const* d_in, const int* in_sizes, int n_in,
                              void* d_out, int out_size, void* d_ws, size_t ws_size,
                              hipStream_t stream) {
    const int* src = (const int*)d_in[0];
    const int* tgt = (const int*)d_in[1];
    const float* emb_src = (const float*)d_in[2];
    const float* emb_tgt = (const float*)d_in[3];
    const float* enc_attn_w = (const float*)d_in[4];
    const float* enc_attn_b = (const float*)d_in[5];
    const float* enc_ff_w1 = (const float*)d_in[6];
    const float* enc_ff_b1 = (const float*)d_in[7];
    const float* enc_ff_w2 = (const float*)d_in[8];
    const float* enc_ff_b2 = (const float*)d_in[9];
    const float* enc_ln_g = (const float*)d_in[10];
    const float* enc_ln_b = (const float*)d_in[11];
    const float* dec_attn_w = (const float*)d_in[12];
    const float* dec_attn_b = (const float*)d_in[13];
    const float* dec_ff_w1 = (const float*)d_in[14];
    const float* dec_ff_b1 = (const float*)d_in[15];
    const float* dec_ff_w2 = (const float*)d_in[16];
    const float* dec_ff_b2 = (const float*)d_in[17];
    const float* dec_ln_g = (const float*)d_in[18];
    const float* dec_ln_b = (const float*)d_in[19];
    const float* fc_w = (const float*)d_in[20];
    const float* fc_b = (const float*)d_in[21];
    float* out = (float*)d_out;

    float* ws = (float*)d_ws;
    const size_t NTOK = (size_t)MROWS * D;   // 1M floats
    float* xe = ws;
    float* xd = xe + NTOK;
    float* qb = xd + NTOK;        // qb,kb,vb contiguous (z-batched QKV)
    float* kb = qb + NTOK;
    float* vb = kb + NTOK;
    float* ab = vb + NTOK;
    float* tb = ab + NTOK;
    float* hb = tb + NTOK;        // 4M floats
    ushort* u0 = (ushort*)(hb + (size_t)MROWS * HID);
    const size_t DD = (size_t)D * D;
    const size_t FCE = (size_t)D * NVT;
    const size_t act_bytes = (size_t)(7 * NTOK + (size_t)MROWS * HID) * 4;
    // batched mode: all weights transposed once up front (7 dispatches)
    const bool batched = ws_size >= act_bytes + (168 * DD + FCE) * 2 + 1024;

    ushort *bEncA, *bEncF1, *bEncF2, *bDecA, *bDecF1, *bDecF2, *bFC;
    ushort *wA = nullptr, *wF1 = nullptr, *wF2 = nullptr;
    if (batched) {
        bEncA = u0;                   // 24 DD
        bEncF1 = bEncA + 24 * DD;     // 24 DD
        bEncF2 = bEncF1 + 24 * DD;    // 24 DD
        bDecA = bEncF2 + 24 * DD;     // 48 DD
        bDecF1 = bDecA + 48 * DD;     // 24 DD
        bDecF2 = bDecF1 + 24 * DD;    // 24 DD
        bFC = bDecF2 + 24 * DD;       // FCE
    } else {
        wA = u0;                      // 8 DD rotating
        wF1 = wA + 8 * DD;            // 4 DD
        wF2 = wF1 + 4 * DD;           // 4 DD
        bFC = wF2 + 4 * DD;           // FCE
        bEncA = bEncF1 = bEncF2 = bDecA = bDecF1 = bDecF2 = nullptr;
    }

    auto tr = [&](const float* w, ushort* dh, int K, int N, int nz) {
        dim3 grid(N / 64, K / 64, nz);
        wsplit_kernel<<<grid, 256, 0, stream>>>(w, dh, K, N, (size_t)K * N);
    };
    auto gemm64 = [&](const float* A, const ushort* WT,
                      const float* bias, float* C, int M, int N, int K) {
        dim3 grid(M / 64, N / 64, 1);
        gemm_mfma<64, 64, false><<<grid, 256, 0, stream>>>(A, A, WT, bias, C, M, N, K, 0, 0);
    };
    auto gemm128 = [&](const float* A, const ushort* WT,
                       const float* bias, float* C, int M, int N, int K, bool relu) {
        dim3 grid(M / 128, N / 128, 1);
        if (relu)
            gemm_mfma<128, 128, true><<<grid, 256, 0, stream>>>(A, A, WT, bias, C, M, N, K, 0, 0);
        else
            gemm_mfma<128, 128, false><<<grid, 256, 0, stream>>>(A, A, WT, bias, C, M, N, K, 0, 0);
    };
    // fused Q,K,V projection, 64^2 tiles (768 blocks -> full CU coverage)
    auto gemm_qkv = [&](const float* Aq, const float* Akv,
                        const ushort* WT, const float* bi) {
        dim3 grid(MROWS / 64, D / 64, 3);
        gemm_mfma<64, 64, false><<<grid, 256, 0, stream>>>(Aq, Akv, WT, bi, qb,
                                                           MROWS, D, D, DD, NTOK);
    };

    if (batched) {
        tr(enc_attn_w, bEncA, D, D, 4 * NL);
        tr(enc_ff_w1, bEncF1, D, HID, NL);
        tr(enc_ff_w2, bEncF2, HID, D, NL);
        tr(dec_attn_w, bDecA, D, D, 8 * NL);
        tr(dec_ff_w1, bDecF1, D, HID, NL);
        tr(dec_ff_w2, bDecF2, HID, D, NL);
        tr(fc_w, bFC, D, NVT, 1);
    }

    embed2_kernel<<<dim3(MROWS, 2), 128, 0, stream>>>(src, tgt, emb_src, emb_tgt, xe, xd);

    const dim3 attn_grid(SEQ / 64, BATCH * NH);

    // ---------------- encoder ----------------
    for (int l = 0; l < NL; ++l) {
        const float* bi = enc_attn_b + (size_t)l * 4 * D;
        ushort* eA;
        ushort* eF1;
        ushort* eF2;
        if (batched) {
            eA = bEncA + (size_t)l * 4 * DD;
            eF1 = bEncF1 + (size_t)l * 4 * DD;
            eF2 = bEncF2 + (size_t)l * 4 * DD;
        } else {
            eA = wA; eF1 = wF1; eF2 = wF2;
            tr(enc_attn_w + (size_t)l * 4 * DD, wA, D, D, 4);
            tr(enc_ff_w1 + (size_t)l * D * HID, wF1, D, HID, 1);
            tr(enc_ff_w2 + (size_t)l * HID * D, wF2, HID, D, 1);
        }

        gemm_qkv(xe, xe, eA, bi);
        attn_mfma<0><<<attn_grid, 256, 0, stream>>>(qb, kb, vb, src, ab);
        gemm64(ab, eA + 3 * DD, bi + 3 * D, tb, MROWS, D, D);
        add_ln_kernel<<<MROWS, 128, 0, stream>>>(xe, tb,
            enc_ln_g + (size_t)(l * 2 + 0) * D, enc_ln_b + (size_t)(l * 2 + 0) * D);
        gemm128(xe, eF1, enc_ff_b1 + (size_t)l * HID, hb, MROWS, HID, D, true);
        gemm64(hb, eF2, enc_ff_b2 + (size_t)l * D, tb, MROWS, D, HID);
        add_ln_kernel<<<MROWS, 128, 0, stream>>>(xe, tb,
            enc_ln_g + (size_t)(l * 2 + 1) * D, enc_ln_b + (size_t)(l * 2 + 1) * D);
    }

    // ---------------- decoder ----------------
    for (int l = 0; l < NL; ++l) {
        ushort* dA;
        ushort* dF1;
        ushort* dF2;
        if (batched) {
            dA = bDecA + (size_t)l * 8 * DD;
            dF1 = bDecF1 + (size_t)l * 4 * DD;
            dF2 = bDecF2 + (size_t)l * 4 * DD;
        } else {
            dA = wA; dF1 = wF1; dF2 = wF2;
            tr(dec_attn_w + (size_t)l * 8 * DD, wA, D, D, 8);
            tr(dec_ff_w1 + (size_t)l * D * HID, wF1, D, HID, 1);
            tr(dec_ff_w2 + (size_t)l * HID * D, wF2, HID, D, 1);
        }
        {   // self-attention (causal + tgt pad mask): slabs 0-3
            const float* bi = dec_attn_b + (size_t)(l * 2 + 0) * 4 * D;
            gemm_qkv(xd, xd, dA, bi);
            attn_mfma<1><<<attn_grid, 256, 0, stream>>>(qb, kb, vb, tgt, ab);
            gemm64(ab, dA + 3 * DD, bi + 3 * D, tb, MROWS, D, D);
            add_ln_kernel<<<MROWS, 128, 0, stream>>>(xd, tb,
                dec_ln_g + (size_t)(l * 3 + 0) * D, dec_ln_b + (size_t)(l * 3 + 0) * D);
        }
        {   // cross-attention: Q from xd, K/V from xe: slabs 4-7
            const float* bi = dec_attn_b + (size_t)(l * 2 + 1) * 4 * D;
            gemm_qkv(xd, xe, dA + 4 * DD, bi);
            attn_mfma<0><<<attn_grid, 256, 0, stream>>>(qb, kb, vb, src, ab);
            gemm64(ab, dA + 7 * DD, bi + 3 * D, tb, MROWS, D, D);
            add_ln_kernel<<<MROWS, 128, 0, stream>>>(xd, tb,
                dec_ln_g + (size_t)(l * 3 + 1) * D, dec_ln_b + (size_t)(l * 3 + 1) * D);
        }
        gemm128(xd, dF1, dec_ff_b1 + (size_t)l * HID, hb, MROWS, HID, D, true);
        gemm64(hb, dF2, dec_ff_b2 + (size_t)l * D, tb, MROWS, D, HID);
        add_ln_kernel<<<MROWS, 128, 0, stream>>>(xd, tb,
            dec_ln_g + (size_t)(l * 3 + 2) * D, dec_ln_b + (size_t)(l * 3 + 2) * D);
    }

    // final projection -> logits [B*T, VT]
    if (!batched) tr(fc_w, bFC, D, NVT, 1);
    {
        dim3 grid(MROWS / 128, NVT / 128, 1);
        gemm_mfma<128, 128, false><<<grid, 256, 0, stream>>>(xd, xd, bFC, fc_b, out,
                                                             MROWS, NVT, D, 0, 0);
    }
}